// Round 1
// baseline (1883.700 us; speedup 1.0000x reference)
//
#include <hip/hip_runtime.h>

// Problem constants (match reference)
#define N_NODES 100000
#define N_EDGES 1600000
#define CCH     128
#define BG      512
#define NHID    512
#define NOUT    256
#define BN_EPS  1e-5f

static __device__ __forceinline__ float leaky(float x) { return x > 0.f ? x : 0.2f * x; }

// ---------------- graph prep ----------------
__global__ void hist_kernel(const int* __restrict__ dst, int* __restrict__ indeg) {
  int e = blockIdx.x * 256 + threadIdx.x;
  if (e < N_EDGES) atomicAdd(&indeg[dst[e]], 1);
}

// chunk = 1024 elements per block (256 threads x 4 contiguous)
__global__ __launch_bounds__(256) void scan_chunks(const int* __restrict__ indeg,
                                                   int* __restrict__ rowstart,
                                                   int* __restrict__ chunksum) {
  int tid = threadIdx.x;
  int base = blockIdx.x * 1024 + tid * 4;
  int4 v;
  if (base + 3 < N_NODES) {
    v = *(const int4*)(indeg + base);
  } else {
    v.x = (base + 0 < N_NODES) ? indeg[base + 0] : 0;
    v.y = (base + 1 < N_NODES) ? indeg[base + 1] : 0;
    v.z = (base + 2 < N_NODES) ? indeg[base + 2] : 0;
    v.w = (base + 3 < N_NODES) ? indeg[base + 3] : 0;
  }
  int s = v.x + v.y + v.z + v.w;
  __shared__ int ss[256];
  ss[tid] = s;
  __syncthreads();
  for (int off = 1; off < 256; off <<= 1) {
    int t = (tid >= off) ? ss[tid - off] : 0;
    __syncthreads();
    ss[tid] += t;
    __syncthreads();
  }
  int excl = ss[tid] - s;
  if (base + 0 < N_NODES) rowstart[base + 0] = excl;
  if (base + 1 < N_NODES) rowstart[base + 1] = excl + v.x;
  if (base + 2 < N_NODES) rowstart[base + 2] = excl + v.x + v.y;
  if (base + 3 < N_NODES) rowstart[base + 3] = excl + v.x + v.y + v.z;
  if (tid == 255) chunksum[blockIdx.x] = ss[255];
}

__global__ void scan_sums(int* __restrict__ chunksum, int nch) {
  __shared__ int ss[128];
  int tid = threadIdx.x;
  int v = (tid < nch) ? chunksum[tid] : 0;
  ss[tid] = v;
  __syncthreads();
  for (int off = 1; off < 128; off <<= 1) {
    int t = (tid >= off) ? ss[tid - off] : 0;
    __syncthreads();
    ss[tid] += t;
    __syncthreads();
  }
  if (tid < nch) chunksum[tid] = ss[tid] - v;  // exclusive
}

__global__ void scan_add(int* __restrict__ rowstart, const int* __restrict__ chunksum) {
  int i = blockIdx.x * 256 + threadIdx.x;
  if (i < N_NODES)      rowstart[i] += chunksum[i >> 10];
  else if (i == N_NODES) rowstart[N_NODES] = N_EDGES;
}

__global__ void scatter_edges(const int* __restrict__ src, const int* __restrict__ dst,
                              const int* __restrict__ rowstart, int* __restrict__ cursor,
                              int* __restrict__ csr_src) {
  int e = blockIdx.x * 256 + threadIdx.x;
  if (e < N_EDGES) {
    int d = dst[e];
    int p = rowstart[d] + atomicAdd(&cursor[d], 1);
    csr_src[p] = src[e];
  }
}

__global__ void compute_dinv(const int* __restrict__ indeg, float* __restrict__ dinv) {
  int i = blockIdx.x * 256 + threadIdx.x;
  if (i < N_NODES) dinv[i] = rsqrtf((float)(indeg[i] + 1));  // deg includes self-loop, >=1
}

// ---------------- GEMM: C[M,N] = A[M,K] @ W[K,N] (+bias)(+relu) ----------------
// 128x128 tile, BK=32, 256 threads, 8x8 microtile per thread.
template <int RELU, int BIAS>
__global__ __launch_bounds__(256) void gemm_f32(const float* __restrict__ A,
                                                const float* __restrict__ W,
                                                const float* __restrict__ bias,
                                                float* __restrict__ Cmat,
                                                int M, int K, int N) {
  __shared__ float As[32][128];  // As[k][m]
  __shared__ float Bs[32][128];  // Bs[k][n]
  int tid = threadIdx.x;
  int row0 = blockIdx.x * 128, col0 = blockIdx.y * 128;
  int tx = tid & 15, ty = tid >> 4;
  float acc[8][8];
#pragma unroll
  for (int i = 0; i < 8; ++i)
#pragma unroll
    for (int j = 0; j < 8; ++j) acc[i][j] = 0.f;

  for (int k0 = 0; k0 < K; k0 += 32) {
    // stage A chunk [128 rows][32 k], transposed into As[k][m]
    {
      int r = tid >> 1;
      int kseg = (tid & 1) * 16;
      bool valid = (row0 + r) < M;
      const float* ap = A + (size_t)(row0 + r) * K + k0 + kseg;
#pragma unroll
      for (int q = 0; q < 4; ++q) {
        float4 v;
        if (valid) v = *(const float4*)(ap + q * 4);
        else { v.x = v.y = v.z = v.w = 0.f; }
        As[kseg + q * 4 + 0][r] = v.x;
        As[kseg + q * 4 + 1][r] = v.y;
        As[kseg + q * 4 + 2][r] = v.z;
        As[kseg + q * 4 + 3][r] = v.w;
      }
    }
    // stage B chunk [32 k][128 n]
    {
      int kk = tid >> 3;
      int seg = (tid & 7) * 16;
      const float* wp = W + (size_t)(k0 + kk) * N + col0 + seg;
#pragma unroll
      for (int q = 0; q < 4; ++q)
        *(float4*)&Bs[kk][seg + q * 4] = *(const float4*)(wp + q * 4);
    }
    __syncthreads();
#pragma unroll
    for (int kk = 0; kk < 32; ++kk) {
      float4 a0 = *(const float4*)&As[kk][ty * 4];
      float4 a1 = *(const float4*)&As[kk][64 + ty * 4];
      float4 b0 = *(const float4*)&Bs[kk][tx * 4];
      float4 b1 = *(const float4*)&Bs[kk][64 + tx * 4];
      float av[8] = {a0.x, a0.y, a0.z, a0.w, a1.x, a1.y, a1.z, a1.w};
      float bv[8] = {b0.x, b0.y, b0.z, b0.w, b1.x, b1.y, b1.z, b1.w};
#pragma unroll
      for (int i = 0; i < 8; ++i)
#pragma unroll
        for (int j = 0; j < 8; ++j) acc[i][j] = fmaf(av[i], bv[j], acc[i][j]);
    }
    __syncthreads();
  }
#pragma unroll
  for (int i = 0; i < 8; ++i) {
    int r = row0 + ((i < 4) ? (ty * 4 + i) : (64 + ty * 4 + i - 4));
    if (r >= M) continue;
#pragma unroll
    for (int j = 0; j < 8; ++j) {
      int c = col0 + ((j < 4) ? (tx * 4 + j) : (64 + tx * 4 + j - 4));
      float v = acc[i][j];
      if (BIAS) v += bias[c];
      if (RELU) v = fmaxf(v, 0.f);
      Cmat[(size_t)r * N + c] = v;
    }
  }
}

// ---------------- GCN aggregation (wave per node) + fused BN stats ----------------
__global__ __launch_bounds__(256) void gcn_agg(const float* __restrict__ h,
                                               const int* __restrict__ rowstart,
                                               const int* __restrict__ csr_src,
                                               const float* __restrict__ dinv,
                                               float* __restrict__ agg,
                                               float* __restrict__ stats) {
  int tid = threadIdx.x;
  int lane = tid & 63;
  int gwave = (blockIdx.x * 256 + tid) >> 6;
  int nwaves = (gridDim.x * 256) >> 6;
  const float2* h2 = (const float2*)h;
  float2* a2 = (float2*)agg;
  float sum0 = 0, sum1 = 0, sq0 = 0, sq1 = 0;
  for (int i = gwave; i < N_NODES; i += nwaves) {
    float di = dinv[i];
    int e0 = rowstart[i], e1 = rowstart[i + 1];
    float2 hi = h2[(size_t)i * 64 + lane];
    float ws = di * di;
    float ax = hi.x * ws, ay = hi.y * ws;
    int e = e0;
    for (; e + 1 < e1; e += 2) {
      int sA = csr_src[e], sB = csr_src[e + 1];
      float wA = dinv[sA] * di, wB = dinv[sB] * di;
      float2 hA = h2[(size_t)sA * 64 + lane];
      float2 hB = h2[(size_t)sB * 64 + lane];
      ax = fmaf(hA.x, wA, ax); ay = fmaf(hA.y, wA, ay);
      ax = fmaf(hB.x, wB, ax); ay = fmaf(hB.y, wB, ay);
    }
    if (e < e1) {
      int sA = csr_src[e];
      float wA = dinv[sA] * di;
      float2 hA = h2[(size_t)sA * 64 + lane];
      ax = fmaf(hA.x, wA, ax); ay = fmaf(hA.y, wA, ay);
    }
    a2[(size_t)i * 64 + lane] = make_float2(ax, ay);
    sum0 += ax; sum1 += ay; sq0 += ax * ax; sq1 += ay * ay;
  }
  __shared__ float red[4][128];
  int w = tid >> 6;
  red[w][2 * lane] = sum0; red[w][2 * lane + 1] = sum1;
  __syncthreads();
  if (w == 0) {
    float a = red[0][2 * lane] + red[1][2 * lane] + red[2][2 * lane] + red[3][2 * lane];
    float b = red[0][2 * lane + 1] + red[1][2 * lane + 1] + red[2][2 * lane + 1] + red[3][2 * lane + 1];
    atomicAdd(&stats[2 * lane], a);
    atomicAdd(&stats[2 * lane + 1], b);
  }
  __syncthreads();
  red[w][2 * lane] = sq0; red[w][2 * lane + 1] = sq1;
  __syncthreads();
  if (w == 0) {
    float a = red[0][2 * lane] + red[1][2 * lane] + red[2][2 * lane] + red[3][2 * lane];
    float b = red[0][2 * lane + 1] + red[1][2 * lane + 1] + red[2][2 * lane + 1] + red[3][2 * lane + 1];
    atomicAdd(&stats[128 + 2 * lane], a);
    atomicAdd(&stats[128 + 2 * lane + 1], b);
  }
}

// ---------------- es/ed for GAT (wave per node, shuffle reduce) ----------------
__global__ __launch_bounds__(256) void compute_esed(const float* __restrict__ h,
                                                    const float* __restrict__ asrc,
                                                    const float* __restrict__ adst,
                                                    float* __restrict__ es, float* __restrict__ ed) {
  int lane = threadIdx.x & 63;
  int gwave = (blockIdx.x * 256 + threadIdx.x) >> 6;
  if (gwave >= N_NODES) return;
  const float2* h2 = (const float2*)h;
  float2 av = ((const float2*)asrc)[lane];
  float2 dv = ((const float2*)adst)[lane];
  float2 hv = h2[(size_t)gwave * 64 + lane];
  float e_s = hv.x * av.x + hv.y * av.y;
  float e_d = hv.x * dv.x + hv.y * dv.y;
  for (int off = 32; off; off >>= 1) {
    e_s += __shfl_down(e_s, off);
    e_d += __shfl_down(e_d, off);
  }
  if (lane == 0) { es[gwave] = e_s; ed[gwave] = e_d; }
}

// ---------------- GAT aggregation (wave per node, 2-pass softmax) + BN stats ----------------
__global__ __launch_bounds__(256) void gat_agg(const float* __restrict__ h,
                                               const int* __restrict__ rowstart,
                                               const int* __restrict__ csr_src,
                                               const float* __restrict__ es,
                                               const float* __restrict__ ed,
                                               float* __restrict__ agg,
                                               float* __restrict__ stats) {
  int tid = threadIdx.x;
  int lane = tid & 63;
  int gwave = (blockIdx.x * 256 + tid) >> 6;
  int nwaves = (gridDim.x * 256) >> 6;
  const float2* h2 = (const float2*)h;
  float2* a2 = (float2*)agg;
  float sum0 = 0, sum1 = 0, sq0 = 0, sq1 = 0;
  for (int i = gwave; i < N_NODES; i += nwaves) {
    float edi = ed[i];
    float esi = es[i];
    int e0 = rowstart[i], e1 = rowstart[i + 1];
    float m = leaky(esi + edi);  // self-loop term
    for (int e = e0; e < e1; ++e)
      m = fmaxf(m, leaky(es[csr_src[e]] + edi));
    float wself = __expf(leaky(esi + edi) - m);
    float2 hi = h2[(size_t)i * 64 + lane];
    float ax = hi.x * wself, ay = hi.y * wself;
    float wsum = wself;
    for (int e = e0; e < e1; ++e) {
      int s = csr_src[e];
      float w = __expf(leaky(es[s] + edi) - m);
      float2 hs = h2[(size_t)s * 64 + lane];
      ax = fmaf(hs.x, w, ax); ay = fmaf(hs.y, w, ay);
      wsum += w;
    }
    float inv = 1.f / (wsum + 1e-16f);
    ax *= inv; ay *= inv;
    a2[(size_t)i * 64 + lane] = make_float2(ax, ay);
    sum0 += ax; sum1 += ay; sq0 += ax * ax; sq1 += ay * ay;
  }
  __shared__ float red[4][128];
  int w = tid >> 6;
  red[w][2 * lane] = sum0; red[w][2 * lane + 1] = sum1;
  __syncthreads();
  if (w == 0) {
    float a = red[0][2 * lane] + red[1][2 * lane] + red[2][2 * lane] + red[3][2 * lane];
    float b = red[0][2 * lane + 1] + red[1][2 * lane + 1] + red[2][2 * lane + 1] + red[3][2 * lane + 1];
    atomicAdd(&stats[2 * lane], a);
    atomicAdd(&stats[2 * lane + 1], b);
  }
  __syncthreads();
  red[w][2 * lane] = sq0; red[w][2 * lane + 1] = sq1;
  __syncthreads();
  if (w == 0) {
    float a = red[0][2 * lane] + red[1][2 * lane] + red[2][2 * lane] + red[3][2 * lane];
    float b = red[0][2 * lane + 1] + red[1][2 * lane + 1] + red[2][2 * lane + 1] + red[3][2 * lane + 1];
    atomicAdd(&stats[128 + 2 * lane], a);
    atomicAdd(&stats[128 + 2 * lane + 1], b);
  }
}

// ---------------- BN(train) + ReLU + residual ----------------
__global__ void bn_relu_res(const float* __restrict__ agg, const float* __restrict__ xin,
                            const float* __restrict__ stats, const float* __restrict__ gamma,
                            const float* __restrict__ beta, float* __restrict__ xout) {
  size_t idx = (size_t)blockIdx.x * 256 + threadIdx.x;  // float2 index
  if (idx >= (size_t)N_NODES * 64) return;
  int c = ((int)(idx & 63)) * 2;
  const float n_inv = 1.f / (float)N_NODES;
  float m0 = stats[c] * n_inv, m1 = stats[c + 1] * n_inv;
  float v0 = stats[128 + c] * n_inv - m0 * m0;
  float v1 = stats[128 + c + 1] * n_inv - m1 * m1;
  float s0 = gamma[c] * rsqrtf(v0 + BN_EPS);
  float s1 = gamma[c + 1] * rsqrtf(v1 + BN_EPS);
  float b0 = beta[c] - m0 * s0;
  float b1 = beta[c + 1] - m1 * s1;
  float2 a = ((const float2*)agg)[idx];
  float2 xi = ((const float2*)xin)[idx];
  float r0 = fmaxf(fmaf(a.x, s0, b0), 0.f) + xi.x;
  float r1 = fmaxf(fmaf(a.y, s1, b1), 0.f) + xi.y;
  ((float2*)xout)[idx] = make_float2(r0, r1);
}

// ---------------- pooling ----------------
__global__ void graph_starts(const int* __restrict__ batch, int* __restrict__ gstart) {
  int n = blockIdx.x * 256 + threadIdx.x;
  if (n >= N_NODES) return;
  int b = batch[n];
  int bp = (n == 0) ? -1 : batch[n - 1];
  for (int g = bp + 1; g <= b; ++g) gstart[g] = n;
  if (n == N_NODES - 1) {
    for (int g = b + 1; g <= BG; ++g) gstart[g] = N_NODES;
  }
}

__global__ __launch_bounds__(256) void pool_kernel(const float* __restrict__ x,
                                                   const int* __restrict__ gstart,
                                                   float* __restrict__ pooled) {
  int g = blockIdx.x;
  int c = threadIdx.x & 127;
  int half = threadIdx.x >> 7;
  int s = gstart[g], e = gstart[g + 1];
  float acc = 0.f;
  for (int n = s + half; n < e; n += 2) acc += x[(size_t)n * 128 + c];
  __shared__ float red[256];
  red[threadIdx.x] = acc;
  __syncthreads();
  if (half == 0) {
    float v = red[c] + red[128 + c];
    int cnt = e - s;
    pooled[(size_t)g * 128 + c] = v / fmaxf((float)cnt, 1.f);
  }
}

// ---------------- host launch ----------------
extern "C" void kernel_launch(void* const* d_in, const int* in_sizes, int n_in,
                              void* d_out, int out_size, void* d_ws, size_t ws_size,
                              hipStream_t stream) {
  const float* x_in  = (const float*)d_in[0];
  const int*   eidx  = (const int*)d_in[1];
  const int*   batch = (const int*)d_in[2];
  const float* W1 = (const float*)d_in[3];
  const float* g1 = (const float*)d_in[5];
  const float* be1 = (const float*)d_in[6];
  const float* W2 = (const float*)d_in[7];
  const float* g2 = (const float*)d_in[9];
  const float* be2 = (const float*)d_in[10];
  const float* W3 = (const float*)d_in[11];
  const float* g3 = (const float*)d_in[13];
  const float* be3 = (const float*)d_in[14];
  const float* Wa = (const float*)d_in[15];
  const float* asrc = (const float*)d_in[16];
  const float* adst = (const float*)d_in[17];
  const float* ga = (const float*)d_in[19];
  const float* bea = (const float*)d_in[20];
  const float* Wh1 = (const float*)d_in[21];
  const float* bh1 = (const float*)d_in[22];
  const float* Wm0 = (const float*)d_in[23];
  const float* bm0 = (const float*)d_in[24];
  const float* Wm1 = (const float*)d_in[25];
  const float* bm1 = (const float*)d_in[26];
  const float* Wo = (const float*)d_in[27];
  const float* bo = (const float*)d_in[28];

  const int* src = eidx;
  const int* dst = eidx + N_EDGES;

  char* p = (char*)d_ws;
  auto alloc = [&](size_t bytes) {
    char* r = p;
    p += (bytes + 255) & ~(size_t)255;
    return r;
  };
  float* h        = (float*)alloc((size_t)N_NODES * CCH * 4);
  float* agg      = (float*)alloc((size_t)N_NODES * CCH * 4);
  float* xbuf     = (float*)alloc((size_t)N_NODES * CCH * 4);
  int*   csr_src  = (int*)alloc((size_t)N_EDGES * 4);
  int*   rowstart = (int*)alloc((size_t)(N_NODES + 1) * 4);
  int*   indeg    = (int*)alloc((size_t)2 * N_NODES * 4);  // indeg + cursor (contiguous, one memset)
  int*   cursor   = indeg + N_NODES;
  float* dinv     = (float*)alloc((size_t)N_NODES * 4);
  float* es       = (float*)alloc((size_t)N_NODES * 4);
  float* ed       = (float*)alloc((size_t)N_NODES * 4);
  int*   chunksum = (int*)alloc(128 * 4);
  float* stats    = (float*)alloc(4 * 256 * 4);  // 4 layers x (sum[128], sumsq[128])
  int*   gstart   = (int*)alloc((BG + 1) * 4);
  float* pooled   = (float*)alloc((size_t)BG * CCH * 4);
  float* m1       = (float*)alloc((size_t)BG * NHID * 4);
  float* m2       = (float*)alloc((size_t)BG * NHID * 4);

  hipMemsetAsync(indeg, 0, (size_t)2 * N_NODES * 4, stream);
  hipMemsetAsync(stats, 0, 4 * 256 * 4, stream);

  // CSR build (shared by all 4 layers)
  hist_kernel<<<(N_EDGES + 255) / 256, 256, 0, stream>>>(dst, indeg);
  scan_chunks<<<98, 256, 0, stream>>>(indeg, rowstart, chunksum);
  scan_sums<<<1, 128, 0, stream>>>(chunksum, 98);
  scan_add<<<(N_NODES + 256) / 256, 256, 0, stream>>>(rowstart, chunksum);
  scatter_edges<<<(N_EDGES + 255) / 256, 256, 0, stream>>>(src, dst, rowstart, cursor, csr_src);
  compute_dinv<<<(N_NODES + 255) / 256, 256, 0, stream>>>(indeg, dinv);

  const int gemm_blocks_m = (N_NODES + 127) / 128;  // 782
  const int bn_blocks = (N_NODES * 64 + 255) / 256; // float2 elements

  const float* xcur = x_in;
  const float* Ws[3] = {W1, W2, W3};
  const float* gs[3] = {g1, g2, g3};
  const float* bes[3] = {be1, be2, be3};
  for (int l = 0; l < 3; ++l) {
    gemm_f32<0, 0><<<dim3(gemm_blocks_m, 1), 256, 0, stream>>>(xcur, Ws[l], nullptr, h, N_NODES, CCH, CCH);
    gcn_agg<<<1024, 256, 0, stream>>>(h, rowstart, csr_src, dinv, agg, stats + l * 256);
    bn_relu_res<<<bn_blocks, 256, 0, stream>>>(agg, xcur, stats + l * 256, gs[l], bes[l], xbuf);
    xcur = xbuf;
  }

  // GAT layer
  gemm_f32<0, 0><<<dim3(gemm_blocks_m, 1), 256, 0, stream>>>(xcur, Wa, nullptr, h, N_NODES, CCH, CCH);
  compute_esed<<<(N_NODES + 3) / 4, 256, 0, stream>>>(h, asrc, adst, es, ed);
  gat_agg<<<1024, 256, 0, stream>>>(h, rowstart, csr_src, es, ed, agg, stats + 3 * 256);
  bn_relu_res<<<bn_blocks, 256, 0, stream>>>(agg, xcur, stats + 3 * 256, ga, bea, xbuf);

  // pooling
  graph_starts<<<(N_NODES + 255) / 256, 256, 0, stream>>>(batch, gstart);
  pool_kernel<<<BG, 256, 0, stream>>>(xbuf, gstart, pooled);

  // MLP head
  gemm_f32<1, 1><<<dim3(4, 4), 256, 0, stream>>>(pooled, Wh1, bh1, m1, BG, CCH, NHID);
  gemm_f32<1, 1><<<dim3(4, 4), 256, 0, stream>>>(m1, Wm0, bm0, m2, BG, NHID, NHID);
  gemm_f32<1, 1><<<dim3(4, 4), 256, 0, stream>>>(m2, Wm1, bm1, m1, BG, NHID, NHID);
  gemm_f32<0, 1><<<dim3(4, 2), 256, 0, stream>>>(m1, Wo, bo, (float*)d_out, BG, NHID, NOUT);
}

// Round 2
// 1572.463 us; speedup vs baseline: 1.1979x; 1.1979x over previous
//
#include <hip/hip_runtime.h>

// Problem constants (match reference)
#define N_NODES 100000
#define N_EDGES 1600000
#define CCH     128
#define BG      512
#define NHID    512
#define NOUT    256
#define BN_EPS  1e-5f

static __device__ __forceinline__ float leaky(float x) { return x > 0.f ? x : 0.2f * x; }

// ---------------- graph prep ----------------
__global__ void hist_kernel(const int* __restrict__ dst, int* __restrict__ indeg) {
  int e = blockIdx.x * 256 + threadIdx.x;
  if (e < N_EDGES) atomicAdd(&indeg[dst[e]], 1);
}

// chunk = 1024 elements per block (256 threads x 4 contiguous)
__global__ __launch_bounds__(256) void scan_chunks(const int* __restrict__ indeg,
                                                   int* __restrict__ rowstart,
                                                   int* __restrict__ chunksum) {
  int tid = threadIdx.x;
  int base = blockIdx.x * 1024 + tid * 4;
  int4 v;
  if (base + 3 < N_NODES) {
    v = *(const int4*)(indeg + base);
  } else {
    v.x = (base + 0 < N_NODES) ? indeg[base + 0] : 0;
    v.y = (base + 1 < N_NODES) ? indeg[base + 1] : 0;
    v.z = (base + 2 < N_NODES) ? indeg[base + 2] : 0;
    v.w = (base + 3 < N_NODES) ? indeg[base + 3] : 0;
  }
  int s = v.x + v.y + v.z + v.w;
  __shared__ int ss[256];
  ss[tid] = s;
  __syncthreads();
  for (int off = 1; off < 256; off <<= 1) {
    int t = (tid >= off) ? ss[tid - off] : 0;
    __syncthreads();
    ss[tid] += t;
    __syncthreads();
  }
  int excl = ss[tid] - s;
  if (base + 0 < N_NODES) rowstart[base + 0] = excl;
  if (base + 1 < N_NODES) rowstart[base + 1] = excl + v.x;
  if (base + 2 < N_NODES) rowstart[base + 2] = excl + v.x + v.y;
  if (base + 3 < N_NODES) rowstart[base + 3] = excl + v.x + v.y + v.z;
  if (tid == 255) chunksum[blockIdx.x] = ss[255];
}

__global__ void scan_sums(int* __restrict__ chunksum, int nch) {
  __shared__ int ss[128];
  int tid = threadIdx.x;
  int v = (tid < nch) ? chunksum[tid] : 0;
  ss[tid] = v;
  __syncthreads();
  for (int off = 1; off < 128; off <<= 1) {
    int t = (tid >= off) ? ss[tid - off] : 0;
    __syncthreads();
    ss[tid] += t;
    __syncthreads();
  }
  if (tid < nch) chunksum[tid] = ss[tid] - v;  // exclusive
}

__global__ void scan_add(int* __restrict__ rowstart, const int* __restrict__ chunksum) {
  int i = blockIdx.x * 256 + threadIdx.x;
  if (i < N_NODES)      rowstart[i] += chunksum[i >> 10];
  else if (i == N_NODES) rowstart[N_NODES] = N_EDGES;
}

__global__ void compute_dinv(const int* __restrict__ indeg, float* __restrict__ dinv) {
  int i = blockIdx.x * 256 + threadIdx.x;
  if (i < N_NODES) dinv[i] = rsqrtf((float)(indeg[i] + 1));  // deg includes self-loop, >=1
}

// scatter edges into CSR, packing {src, norm_weight} per slot (single 8B broadcast load later)
__global__ void scatter_edges(const int* __restrict__ src, const int* __restrict__ dst,
                              const int* __restrict__ rowstart, int* __restrict__ cursor,
                              const float* __restrict__ dinv, int2* __restrict__ csr_sw) {
  int e = blockIdx.x * 256 + threadIdx.x;
  if (e < N_EDGES) {
    int d = dst[e];
    int s = src[e];
    int p = rowstart[d] + atomicAdd(&cursor[d], 1);
    float w = dinv[s] * dinv[d];
    csr_sw[p] = make_int2(s, __float_as_int(w));
  }
}

// ---------------- GEMM: C[M,N] = A[M,K] @ W[K,N] (+bias)(+relu) ----------------
template <int RELU, int BIAS>
__global__ __launch_bounds__(256) void gemm_f32(const float* __restrict__ A,
                                                const float* __restrict__ W,
                                                const float* __restrict__ bias,
                                                float* __restrict__ Cmat,
                                                int M, int K, int N) {
  __shared__ float As[32][128];  // As[k][m]
  __shared__ float Bs[32][128];  // Bs[k][n]
  int tid = threadIdx.x;
  int row0 = blockIdx.x * 128, col0 = blockIdx.y * 128;
  int tx = tid & 15, ty = tid >> 4;
  float acc[8][8];
#pragma unroll
  for (int i = 0; i < 8; ++i)
#pragma unroll
    for (int j = 0; j < 8; ++j) acc[i][j] = 0.f;

  for (int k0 = 0; k0 < K; k0 += 32) {
    {
      int r = tid >> 1;
      int kseg = (tid & 1) * 16;
      bool valid = (row0 + r) < M;
      const float* ap = A + (size_t)(row0 + r) * K + k0 + kseg;
#pragma unroll
      for (int q = 0; q < 4; ++q) {
        float4 v;
        if (valid) v = *(const float4*)(ap + q * 4);
        else { v.x = v.y = v.z = v.w = 0.f; }
        As[kseg + q * 4 + 0][r] = v.x;
        As[kseg + q * 4 + 1][r] = v.y;
        As[kseg + q * 4 + 2][r] = v.z;
        As[kseg + q * 4 + 3][r] = v.w;
      }
    }
    {
      int kk = tid >> 3;
      int seg = (tid & 7) * 16;
      const float* wp = W + (size_t)(k0 + kk) * N + col0 + seg;
#pragma unroll
      for (int q = 0; q < 4; ++q)
        *(float4*)&Bs[kk][seg + q * 4] = *(const float4*)(wp + q * 4);
    }
    __syncthreads();
#pragma unroll
    for (int kk = 0; kk < 32; ++kk) {
      float4 a0 = *(const float4*)&As[kk][ty * 4];
      float4 a1 = *(const float4*)&As[kk][64 + ty * 4];
      float4 b0 = *(const float4*)&Bs[kk][tx * 4];
      float4 b1 = *(const float4*)&Bs[kk][64 + tx * 4];
      float av[8] = {a0.x, a0.y, a0.z, a0.w, a1.x, a1.y, a1.z, a1.w};
      float bv[8] = {b0.x, b0.y, b0.z, b0.w, b1.x, b1.y, b1.z, b1.w};
#pragma unroll
      for (int i = 0; i < 8; ++i)
#pragma unroll
        for (int j = 0; j < 8; ++j) acc[i][j] = fmaf(av[i], bv[j], acc[i][j]);
    }
    __syncthreads();
  }
#pragma unroll
  for (int i = 0; i < 8; ++i) {
    int r = row0 + ((i < 4) ? (ty * 4 + i) : (64 + ty * 4 + i - 4));
    if (r >= M) continue;
#pragma unroll
    for (int j = 0; j < 8; ++j) {
      int c = col0 + ((j < 4) ? (tx * 4 + j) : (64 + tx * 4 + j - 4));
      float v = acc[i][j];
      if (BIAS) v += bias[c];
      if (RELU) v = fmaxf(v, 0.f);
      Cmat[(size_t)r * N + c] = v;
    }
  }
}

// ---------------- GCN aggregation (wave per node) + fused BN stats ----------------
__global__ __launch_bounds__(256) void gcn_agg(const float* __restrict__ h,
                                               const int* __restrict__ rowstart,
                                               const int2* __restrict__ csr_sw,
                                               const float* __restrict__ dinv,
                                               float* __restrict__ agg,
                                               float* __restrict__ stats) {
  int tid = threadIdx.x;
  int lane = tid & 63;
  int gwave = (blockIdx.x * 256 + tid) >> 6;
  int nwaves = (gridDim.x * 256) >> 6;
  const float2* h2 = (const float2*)h;
  float2* a2 = (float2*)agg;
  float sum0 = 0, sum1 = 0, sq0 = 0, sq1 = 0;
  for (int i = gwave; i < N_NODES; i += nwaves) {
    float di = dinv[i];
    int e0 = rowstart[i], e1 = rowstart[i + 1];
    float2 hi = h2[(size_t)i * 64 + lane];
    float ws = di * di;
    float ax0 = hi.x * ws, ay0 = hi.y * ws;
    float ax1 = 0.f, ay1 = 0.f, ax2 = 0.f, ay2 = 0.f, ax3 = 0.f, ay3 = 0.f;
    int e = e0;
    for (; e + 3 < e1; e += 4) {
      int2 p0 = csr_sw[e], p1 = csr_sw[e + 1], p2 = csr_sw[e + 2], p3 = csr_sw[e + 3];
      float2 hA = h2[(size_t)p0.x * 64 + lane];
      float2 hB = h2[(size_t)p1.x * 64 + lane];
      float2 hC = h2[(size_t)p2.x * 64 + lane];
      float2 hD = h2[(size_t)p3.x * 64 + lane];
      ax0 = fmaf(hA.x, __int_as_float(p0.y), ax0); ay0 = fmaf(hA.y, __int_as_float(p0.y), ay0);
      ax1 = fmaf(hB.x, __int_as_float(p1.y), ax1); ay1 = fmaf(hB.y, __int_as_float(p1.y), ay1);
      ax2 = fmaf(hC.x, __int_as_float(p2.y), ax2); ay2 = fmaf(hC.y, __int_as_float(p2.y), ay2);
      ax3 = fmaf(hD.x, __int_as_float(p3.y), ax3); ay3 = fmaf(hD.y, __int_as_float(p3.y), ay3);
    }
    for (; e < e1; ++e) {
      int2 p = csr_sw[e];
      float2 hA = h2[(size_t)p.x * 64 + lane];
      ax0 = fmaf(hA.x, __int_as_float(p.y), ax0);
      ay0 = fmaf(hA.y, __int_as_float(p.y), ay0);
    }
    float ax = (ax0 + ax1) + (ax2 + ax3);
    float ay = (ay0 + ay1) + (ay2 + ay3);
    a2[(size_t)i * 64 + lane] = make_float2(ax, ay);
    sum0 += ax; sum1 += ay; sq0 += ax * ax; sq1 += ay * ay;
  }
  __shared__ float red[4][128];
  int w = tid >> 6;
  red[w][2 * lane] = sum0; red[w][2 * lane + 1] = sum1;
  __syncthreads();
  if (w == 0) {
    float a = red[0][2 * lane] + red[1][2 * lane] + red[2][2 * lane] + red[3][2 * lane];
    float b = red[0][2 * lane + 1] + red[1][2 * lane + 1] + red[2][2 * lane + 1] + red[3][2 * lane + 1];
    atomicAdd(&stats[2 * lane], a);
    atomicAdd(&stats[2 * lane + 1], b);
  }
  __syncthreads();
  red[w][2 * lane] = sq0; red[w][2 * lane + 1] = sq1;
  __syncthreads();
  if (w == 0) {
    float a = red[0][2 * lane] + red[1][2 * lane] + red[2][2 * lane] + red[3][2 * lane];
    float b = red[0][2 * lane + 1] + red[1][2 * lane + 1] + red[2][2 * lane + 1] + red[3][2 * lane + 1];
    atomicAdd(&stats[128 + 2 * lane], a);
    atomicAdd(&stats[128 + 2 * lane + 1], b);
  }
}

// ---------------- es/ed for GAT (wave per node, shuffle reduce) ----------------
__global__ __launch_bounds__(256) void compute_esed(const float* __restrict__ h,
                                                    const float* __restrict__ asrc,
                                                    const float* __restrict__ adst,
                                                    float* __restrict__ es, float* __restrict__ ed) {
  int lane = threadIdx.x & 63;
  int gwave = (blockIdx.x * 256 + threadIdx.x) >> 6;
  if (gwave >= N_NODES) return;
  const float2* h2 = (const float2*)h;
  float2 av = ((const float2*)asrc)[lane];
  float2 dv = ((const float2*)adst)[lane];
  float2 hv = h2[(size_t)gwave * 64 + lane];
  float e_s = hv.x * av.x + hv.y * av.y;
  float e_d = hv.x * dv.x + hv.y * dv.y;
  for (int off = 32; off; off >>= 1) {
    e_s += __shfl_down(e_s, off);
    e_d += __shfl_down(e_d, off);
  }
  if (lane == 0) { es[gwave] = e_s; ed[gwave] = e_d; }
}

// overwrite csr_sw (dead after GCN layers) in-place with {src, es[src]} for GAT
__global__ void gat_pack_kernel(int2* __restrict__ sw, const float* __restrict__ es) {
  int e = blockIdx.x * 256 + threadIdx.x;
  if (e < N_EDGES) {
    int2 v = sw[e];
    v.y = __float_as_int(es[v.x]);
    sw[e] = v;
  }
}

// ---------------- GAT aggregation (wave per node, no-max softmax) + BN stats ----------------
// exp(e)/sum(exp(e)) == exp(e-m)/sum(exp(e-m)); |e| <= ~10 so no overflow risk in f32.
__global__ __launch_bounds__(256) void gat_agg(const float* __restrict__ h,
                                               const int* __restrict__ rowstart,
                                               const int2* __restrict__ gpack,
                                               const float* __restrict__ es,
                                               const float* __restrict__ ed,
                                               float* __restrict__ agg,
                                               float* __restrict__ stats) {
  int tid = threadIdx.x;
  int lane = tid & 63;
  int gwave = (blockIdx.x * 256 + tid) >> 6;
  int nwaves = (gridDim.x * 256) >> 6;
  const float2* h2 = (const float2*)h;
  float2* a2 = (float2*)agg;
  float sum0 = 0, sum1 = 0, sq0 = 0, sq1 = 0;
  for (int i = gwave; i < N_NODES; i += nwaves) {
    float edi = ed[i];
    float esi = es[i];
    int e0 = rowstart[i], e1 = rowstart[i + 1];
    float wself = __expf(leaky(esi + edi));
    // lane-parallel softmax denominator
    float wsum = (lane == 0) ? wself : 0.f;
    for (int e = e0 + lane; e < e1; e += 64)
      wsum += __expf(leaky(__int_as_float(gpack[e].y) + edi));
    for (int off = 32; off; off >>= 1) wsum += __shfl_xor(wsum, off);
    float inv = 1.f / (wsum + 1e-16f);
    // gather pass
    float2 hi = h2[(size_t)i * 64 + lane];
    float wS = wself * inv;
    float axA = hi.x * wS, ayA = hi.y * wS, axB = 0.f, ayB = 0.f;
    int e = e0;
    for (; e + 1 < e1; e += 2) {
      int2 pA = gpack[e], pB = gpack[e + 1];
      float wA = __expf(leaky(__int_as_float(pA.y) + edi)) * inv;
      float wB = __expf(leaky(__int_as_float(pB.y) + edi)) * inv;
      float2 hA = h2[(size_t)pA.x * 64 + lane];
      float2 hB = h2[(size_t)pB.x * 64 + lane];
      axA = fmaf(hA.x, wA, axA); ayA = fmaf(hA.y, wA, ayA);
      axB = fmaf(hB.x, wB, axB); ayB = fmaf(hB.y, wB, ayB);
    }
    if (e < e1) {
      int2 pA = gpack[e];
      float wA = __expf(leaky(__int_as_float(pA.y) + edi)) * inv;
      float2 hA = h2[(size_t)pA.x * 64 + lane];
      axA = fmaf(hA.x, wA, axA); ayA = fmaf(hA.y, wA, ayA);
    }
    float ax = axA + axB, ay = ayA + ayB;
    a2[(size_t)i * 64 + lane] = make_float2(ax, ay);
    sum0 += ax; sum1 += ay; sq0 += ax * ax; sq1 += ay * ay;
  }
  __shared__ float red[4][128];
  int w = tid >> 6;
  red[w][2 * lane] = sum0; red[w][2 * lane + 1] = sum1;
  __syncthreads();
  if (w == 0) {
    float a = red[0][2 * lane] + red[1][2 * lane] + red[2][2 * lane] + red[3][2 * lane];
    float b = red[0][2 * lane + 1] + red[1][2 * lane + 1] + red[2][2 * lane + 1] + red[3][2 * lane + 1];
    atomicAdd(&stats[2 * lane], a);
    atomicAdd(&stats[2 * lane + 1], b);
  }
  __syncthreads();
  red[w][2 * lane] = sq0; red[w][2 * lane + 1] = sq1;
  __syncthreads();
  if (w == 0) {
    float a = red[0][2 * lane] + red[1][2 * lane] + red[2][2 * lane] + red[3][2 * lane];
    float b = red[0][2 * lane + 1] + red[1][2 * lane + 1] + red[2][2 * lane + 1] + red[3][2 * lane + 1];
    atomicAdd(&stats[128 + 2 * lane], a);
    atomicAdd(&stats[128 + 2 * lane + 1], b);
  }
}

// ---------------- BN(train) + ReLU + residual ----------------
__global__ void bn_relu_res(const float* __restrict__ agg, const float* __restrict__ xin,
                            const float* __restrict__ stats, const float* __restrict__ gamma,
                            const float* __restrict__ beta, float* __restrict__ xout) {
  size_t idx = (size_t)blockIdx.x * 256 + threadIdx.x;  // float2 index
  if (idx >= (size_t)N_NODES * 64) return;
  int c = ((int)(idx & 63)) * 2;
  const float n_inv = 1.f / (float)N_NODES;
  float m0 = stats[c] * n_inv, m1 = stats[c + 1] * n_inv;
  float v0 = stats[128 + c] * n_inv - m0 * m0;
  float v1 = stats[128 + c + 1] * n_inv - m1 * m1;
  float s0 = gamma[c] * rsqrtf(v0 + BN_EPS);
  float s1 = gamma[c + 1] * rsqrtf(v1 + BN_EPS);
  float b0 = beta[c] - m0 * s0;
  float b1 = beta[c + 1] - m1 * s1;
  float2 a = ((const float2*)agg)[idx];
  float2 xi = ((const float2*)xin)[idx];
  float r0 = fmaxf(fmaf(a.x, s0, b0), 0.f) + xi.x;
  float r1 = fmaxf(fmaf(a.y, s1, b1), 0.f) + xi.y;
  ((float2*)xout)[idx] = make_float2(r0, r1);
}

// ---------------- pooling ----------------
__global__ void graph_starts(const int* __restrict__ batch, int* __restrict__ gstart) {
  int n = blockIdx.x * 256 + threadIdx.x;
  if (n >= N_NODES) return;
  int b = batch[n];
  int bp = (n == 0) ? -1 : batch[n - 1];
  for (int g = bp + 1; g <= b; ++g) gstart[g] = n;
  if (n == N_NODES - 1) {
    for (int g = b + 1; g <= BG; ++g) gstart[g] = N_NODES;
  }
}

__global__ __launch_bounds__(256) void pool_kernel(const float* __restrict__ x,
                                                   const int* __restrict__ gstart,
                                                   float* __restrict__ pooled) {
  int g = blockIdx.x;
  int c = threadIdx.x & 127;
  int half = threadIdx.x >> 7;
  int s = gstart[g], e = gstart[g + 1];
  float acc = 0.f;
  for (int n = s + half; n < e; n += 2) acc += x[(size_t)n * 128 + c];
  __shared__ float red[256];
  red[threadIdx.x] = acc;
  __syncthreads();
  if (half == 0) {
    float v = red[c] + red[128 + c];
    int cnt = e - s;
    pooled[(size_t)g * 128 + c] = v / fmaxf((float)cnt, 1.f);
  }
}

// ---------------- host launch ----------------
extern "C" void kernel_launch(void* const* d_in, const int* in_sizes, int n_in,
                              void* d_out, int out_size, void* d_ws, size_t ws_size,
                              hipStream_t stream) {
  const float* x_in  = (const float*)d_in[0];
  const int*   eidx  = (const int*)d_in[1];
  const int*   batch = (const int*)d_in[2];
  const float* W1 = (const float*)d_in[3];
  const float* g1 = (const float*)d_in[5];
  const float* be1 = (const float*)d_in[6];
  const float* W2 = (const float*)d_in[7];
  const float* g2 = (const float*)d_in[9];
  const float* be2 = (const float*)d_in[10];
  const float* W3 = (const float*)d_in[11];
  const float* g3 = (const float*)d_in[13];
  const float* be3 = (const float*)d_in[14];
  const float* Wa = (const float*)d_in[15];
  const float* asrc = (const float*)d_in[16];
  const float* adst = (const float*)d_in[17];
  const float* ga = (const float*)d_in[19];
  const float* bea = (const float*)d_in[20];
  const float* Wh1 = (const float*)d_in[21];
  const float* bh1 = (const float*)d_in[22];
  const float* Wm0 = (const float*)d_in[23];
  const float* bm0 = (const float*)d_in[24];
  const float* Wm1 = (const float*)d_in[25];
  const float* bm1 = (const float*)d_in[26];
  const float* Wo = (const float*)d_in[27];
  const float* bo = (const float*)d_in[28];

  const int* src = eidx;
  const int* dst = eidx + N_EDGES;

  char* p = (char*)d_ws;
  auto alloc = [&](size_t bytes) {
    char* r = p;
    p += (bytes + 255) & ~(size_t)255;
    return r;
  };
  float* h        = (float*)alloc((size_t)N_NODES * CCH * 4);
  float* agg      = (float*)alloc((size_t)N_NODES * CCH * 4);
  float* xbuf     = (float*)alloc((size_t)N_NODES * CCH * 4);
  int2*  csr_sw   = (int2*)alloc((size_t)N_EDGES * 8);   // {src, weight} / later {src, es[src]}
  int*   rowstart = (int*)alloc((size_t)(N_NODES + 1) * 4);
  int*   indeg    = (int*)alloc((size_t)2 * N_NODES * 4);  // indeg + cursor (one memset)
  int*   cursor   = indeg + N_NODES;
  float* dinv     = (float*)alloc((size_t)N_NODES * 4);
  float* es       = (float*)alloc((size_t)N_NODES * 4);
  float* ed       = (float*)alloc((size_t)N_NODES * 4);
  int*   chunksum = (int*)alloc(128 * 4);
  float* stats    = (float*)alloc(4 * 256 * 4);  // 4 layers x (sum[128], sumsq[128])
  int*   gstart   = (int*)alloc((BG + 1) * 4);
  float* pooled   = (float*)alloc((size_t)BG * CCH * 4);
  float* m1       = (float*)alloc((size_t)BG * NHID * 4);
  float* m2       = (float*)alloc((size_t)BG * NHID * 4);

  hipMemsetAsync(indeg, 0, (size_t)2 * N_NODES * 4, stream);
  hipMemsetAsync(stats, 0, 4 * 256 * 4, stream);

  // CSR build (shared by all 4 layers)
  hist_kernel<<<(N_EDGES + 255) / 256, 256, 0, stream>>>(dst, indeg);
  scan_chunks<<<98, 256, 0, stream>>>(indeg, rowstart, chunksum);
  scan_sums<<<1, 128, 0, stream>>>(chunksum, 98);
  scan_add<<<(N_NODES + 256) / 256, 256, 0, stream>>>(rowstart, chunksum);
  compute_dinv<<<(N_NODES + 255) / 256, 256, 0, stream>>>(indeg, dinv);
  scatter_edges<<<(N_EDGES + 255) / 256, 256, 0, stream>>>(src, dst, rowstart, cursor, dinv, csr_sw);

  const int gemm_blocks_m = (N_NODES + 127) / 128;  // 782
  const int bn_blocks = (N_NODES * 64 + 255) / 256; // float2 elements
  const int AGG_BLOCKS = 2048;                      // 8192 waves = full chip

  const float* xcur = x_in;
  const float* Ws[3] = {W1, W2, W3};
  const float* gs[3] = {g1, g2, g3};
  const float* bes[3] = {be1, be2, be3};
  for (int l = 0; l < 3; ++l) {
    gemm_f32<0, 0><<<dim3(gemm_blocks_m, 1), 256, 0, stream>>>(xcur, Ws[l], nullptr, h, N_NODES, CCH, CCH);
    gcn_agg<<<AGG_BLOCKS, 256, 0, stream>>>(h, rowstart, csr_sw, dinv, agg, stats + l * 256);
    bn_relu_res<<<bn_blocks, 256, 0, stream>>>(agg, xcur, stats + l * 256, gs[l], bes[l], xbuf);
    xcur = xbuf;
  }

  // GAT layer
  gemm_f32<0, 0><<<dim3(gemm_blocks_m, 1), 256, 0, stream>>>(xcur, Wa, nullptr, h, N_NODES, CCH, CCH);
  compute_esed<<<(N_NODES + 3) / 4, 256, 0, stream>>>(h, asrc, adst, es, ed);
  gat_pack_kernel<<<(N_EDGES + 255) / 256, 256, 0, stream>>>(csr_sw, es);
  gat_agg<<<AGG_BLOCKS, 256, 0, stream>>>(h, rowstart, csr_sw, es, ed, agg, stats + 3 * 256);
  bn_relu_res<<<bn_blocks, 256, 0, stream>>>(agg, xcur, stats + 3 * 256, ga, bea, xbuf);

  // pooling
  graph_starts<<<(N_NODES + 255) / 256, 256, 0, stream>>>(batch, gstart);
  pool_kernel<<<BG, 256, 0, stream>>>(xbuf, gstart, pooled);

  // MLP head
  gemm_f32<1, 1><<<dim3(4, 4), 256, 0, stream>>>(pooled, Wh1, bh1, m1, BG, CCH, NHID);
  gemm_f32<1, 1><<<dim3(4, 4), 256, 0, stream>>>(m1, Wm0, bm0, m2, BG, NHID, NHID);
  gemm_f32<1, 1><<<dim3(4, 4), 256, 0, stream>>>(m2, Wm1, bm1, m1, BG, NHID, NHID);
  gemm_f32<0, 1><<<dim3(4, 2), 256, 0, stream>>>(m1, Wo, bo, (float*)d_out, BG, NHID, NOUT);
}

// Round 3
// 1314.790 us; speedup vs baseline: 1.4327x; 1.1960x over previous
//
#include <hip/hip_runtime.h>

// Problem constants (match reference)
#define N_NODES 100000
#define N_EDGES 1600000
#define CCH     128
#define BG      512
#define NHID    512
#define NOUT    256
#define BN_EPS  1e-5f

typedef __attribute__((ext_vector_type(8))) short s16x8;
typedef __attribute__((ext_vector_type(4))) float f32x4;

static __device__ __forceinline__ float leaky(float x) { return x > 0.f ? x : 0.2f * x; }
// bf16 round-to-nearest-even, returns low 16 bits
static __device__ __forceinline__ uint32_t bfr16(float x) {
  uint32_t u = __float_as_uint(x);
  u += 0x7fffu + ((u >> 16) & 1u);
  return u >> 16;
}
static __device__ __forceinline__ uint32_t pack2(float a, float b) {
  return bfr16(a) | (bfr16(b) << 16);
}
static __device__ __forceinline__ float blo(uint32_t u) { return __uint_as_float(u << 16); }
static __device__ __forceinline__ float bhi(uint32_t u) { return __uint_as_float(u & 0xffff0000u); }

// ---------------- graph prep ----------------
__global__ void hist_kernel(const int* __restrict__ dst, int* __restrict__ indeg) {
  int e = blockIdx.x * 256 + threadIdx.x;
  if (e < N_EDGES) atomicAdd(&indeg[dst[e]], 1);
}

__global__ __launch_bounds__(256) void scan_chunks(const int* __restrict__ indeg,
                                                   int* __restrict__ rowstart,
                                                   int* __restrict__ chunksum) {
  int tid = threadIdx.x;
  int base = blockIdx.x * 1024 + tid * 4;
  int4 v;
  if (base + 3 < N_NODES) {
    v = *(const int4*)(indeg + base);
  } else {
    v.x = (base + 0 < N_NODES) ? indeg[base + 0] : 0;
    v.y = (base + 1 < N_NODES) ? indeg[base + 1] : 0;
    v.z = (base + 2 < N_NODES) ? indeg[base + 2] : 0;
    v.w = (base + 3 < N_NODES) ? indeg[base + 3] : 0;
  }
  int s = v.x + v.y + v.z + v.w;
  __shared__ int ss[256];
  ss[tid] = s;
  __syncthreads();
  for (int off = 1; off < 256; off <<= 1) {
    int t = (tid >= off) ? ss[tid - off] : 0;
    __syncthreads();
    ss[tid] += t;
    __syncthreads();
  }
  int excl = ss[tid] - s;
  if (base + 0 < N_NODES) rowstart[base + 0] = excl;
  if (base + 1 < N_NODES) rowstart[base + 1] = excl + v.x;
  if (base + 2 < N_NODES) rowstart[base + 2] = excl + v.x + v.y;
  if (base + 3 < N_NODES) rowstart[base + 3] = excl + v.x + v.y + v.z;
  if (tid == 255) chunksum[blockIdx.x] = ss[255];
}

__global__ void scan_sums(int* __restrict__ chunksum, int nch) {
  __shared__ int ss[128];
  int tid = threadIdx.x;
  int v = (tid < nch) ? chunksum[tid] : 0;
  ss[tid] = v;
  __syncthreads();
  for (int off = 1; off < 128; off <<= 1) {
    int t = (tid >= off) ? ss[tid - off] : 0;
    __syncthreads();
    ss[tid] += t;
    __syncthreads();
  }
  if (tid < nch) chunksum[tid] = ss[tid] - v;  // exclusive
}

__global__ void scan_add(int* __restrict__ rowstart, const int* __restrict__ chunksum) {
  int i = blockIdx.x * 256 + threadIdx.x;
  if (i < N_NODES)      rowstart[i] += chunksum[i >> 10];
  else if (i == N_NODES) rowstart[N_NODES] = N_EDGES;
}

__global__ void compute_dinv(const int* __restrict__ indeg, float* __restrict__ dinv) {
  int i = blockIdx.x * 256 + threadIdx.x;
  if (i < N_NODES) dinv[i] = rsqrtf((float)(indeg[i] + 1));
}

__global__ void scatter_edges(const int* __restrict__ src, const int* __restrict__ dst,
                              const int* __restrict__ rowstart, int* __restrict__ cursor,
                              const float* __restrict__ dinv, int2* __restrict__ csr_sw) {
  int e = blockIdx.x * 256 + threadIdx.x;
  if (e < N_EDGES) {
    int d = dst[e];
    int s = src[e];
    int p = rowstart[d] + atomicAdd(&cursor[d], 1);
    float w = dinv[s] * dinv[d];
    csr_sw[p] = make_int2(s, __float_as_int(w));
  }
}

// ---------------- bf16 helpers: cast input x, pack weights ----------------
__global__ void cast_bf16_kernel(const float2* __restrict__ x2, uint32_t* __restrict__ xb) {
  size_t idx = (size_t)blockIdx.x * 256 + threadIdx.x;
  if (idx >= (size_t)N_NODES * 64) return;
  float2 v = x2[idx];
  xb[idx] = pack2(v.x, v.y);
}

// pack W[128][128] f32 into MFMA b-frag order: Wp[(nt*4+ks)*64 + lane][i] (ushort)
// b-frag (16x16x32): col = lane&15 (+16*nt), k = ks*32 + (lane>>4)*8 + i
__global__ void pack_w_kernel(const float* __restrict__ W, unsigned short* __restrict__ Wp) {
  int t = blockIdx.x * 256 + threadIdx.x;
  if (t >= 2048) return;
  int lane = t & 63;
  int ks = (t >> 6) & 3;
  int nt = t >> 8;
  int c = nt * 16 + (lane & 15);
  int kb = ks * 32 + (lane >> 4) * 8;
#pragma unroll
  for (int i = 0; i < 8; ++i)
    Wp[(size_t)t * 8 + i] = (unsigned short)bfr16(W[(size_t)(kb + i) * 128 + c]);
}

// ---------------- MFMA conv GEMM: Hb[M][64]u32 = bf16( Ab[M][128] @ W ) ----------------
// 782 blocks x 256 thr (4 waves); wave computes 32 rows x 128 cols; no LDS.
__global__ __launch_bounds__(256) void gemm_mfma(const uint32_t* __restrict__ Ab,   // [M][64] packed bf16 pairs
                                                 const unsigned short* __restrict__ Wp,
                                                 uint32_t* __restrict__ Hb,          // [M][64] packed bf16 pairs
                                                 int M) {
  int wave = threadIdx.x >> 6, lane = threadIdx.x & 63;
  int row0 = blockIdx.x * 128 + wave * 32;
  const unsigned short* A16 = (const unsigned short*)Ab;

  f32x4 acc[2][8];
#pragma unroll
  for (int mt = 0; mt < 2; ++mt)
#pragma unroll
    for (int nt = 0; nt < 8; ++nt) acc[mt][nt] = (f32x4){0.f, 0.f, 0.f, 0.f};

  // a-frags: row = row0 + mt*16 + (lane&15); k = ks*32 + (lane>>4)*8 + i
  s16x8 a[2][4];
  int r = lane & 15, ko = (lane >> 4) * 8;
#pragma unroll
  for (int mt = 0; mt < 2; ++mt) {
    int row = row0 + mt * 16 + r;
    bool v = row < M;
    const unsigned short* ap = A16 + (size_t)row * 128 + ko;
#pragma unroll
    for (int ks = 0; ks < 4; ++ks) {
      s16x8 af = {0, 0, 0, 0, 0, 0, 0, 0};
      if (v) af = *(const s16x8*)(ap + ks * 32);
      a[mt][ks] = af;
    }
  }
#pragma unroll
  for (int ks = 0; ks < 4; ++ks) {
#pragma unroll
    for (int nt = 0; nt < 8; ++nt) {
      s16x8 b = *(const s16x8*)(Wp + ((size_t)(nt * 4 + ks) * 64 + lane) * 8);
      acc[0][nt] = __builtin_amdgcn_mfma_f32_16x16x32_bf16(a[0][ks], b, acc[0][nt], 0, 0, 0);
      acc[1][nt] = __builtin_amdgcn_mfma_f32_16x16x32_bf16(a[1][ks], b, acc[1][nt], 0, 0, 0);
    }
  }
  // epilogue: row = row0 + mt*16 + (lane>>4)*4 + reg; col = nt*16 + (lane&15)
#pragma unroll
  for (int mt = 0; mt < 2; ++mt) {
#pragma unroll
    for (int nt = 0; nt < 8; ++nt) {
#pragma unroll
      for (int reg = 0; reg < 4; ++reg) {
        float v0 = acc[mt][nt][reg];
        float v1 = __shfl_xor(v0, 1);
        int row = row0 + mt * 16 + (lane >> 4) * 4 + reg;
        int col = nt * 16 + (lane & 15);
        if (!(lane & 1) && row < M)
          Hb[(size_t)row * 64 + (col >> 1)] = pack2(v0, v1);
      }
    }
  }
}

// ---------------- GCN aggregation (wave per node, bf16 rows, pipelined) + BN stats ----------------
__global__ __launch_bounds__(256) void gcn_agg(const uint32_t* __restrict__ Hb,
                                               const int* __restrict__ rowstart,
                                               const int2* __restrict__ csr_sw,
                                               const float* __restrict__ dinv,
                                               float* __restrict__ agg,
                                               float* __restrict__ stats) {
  int tid = threadIdx.x;
  int lane = tid & 63;
  int gwave = (blockIdx.x * 256 + tid) >> 6;
  int nwaves = (gridDim.x * 256) >> 6;
  float2* a2 = (float2*)agg;
  float sum0 = 0, sum1 = 0, sq0 = 0, sq1 = 0;
  for (int i = gwave; i < N_NODES; i += nwaves) {
    float di = dinv[i];
    int e0 = rowstart[i], e1 = rowstart[i + 1];
    uint32_t hs = Hb[(size_t)i * 64 + lane];
    float ws = di * di;
    float ax0 = blo(hs) * ws, ay0 = bhi(hs) * ws;
    float ax1 = 0.f, ay1 = 0.f, ax2 = 0.f, ay2 = 0.f, ax3 = 0.f, ay3 = 0.f;
    int e = e0;
    if (e + 4 <= e1) {
      int2 p0 = csr_sw[e], p1 = csr_sw[e + 1], p2 = csr_sw[e + 2], p3 = csr_sw[e + 3];
      e += 4;
      while (e + 4 <= e1) {
        uint32_t hA = Hb[(size_t)p0.x * 64 + lane];
        uint32_t hB = Hb[(size_t)p1.x * 64 + lane];
        uint32_t hC = Hb[(size_t)p2.x * 64 + lane];
        uint32_t hD = Hb[(size_t)p3.x * 64 + lane];
        float w0 = __int_as_float(p0.y), w1 = __int_as_float(p1.y);
        float w2 = __int_as_float(p2.y), w3 = __int_as_float(p3.y);
        p0 = csr_sw[e]; p1 = csr_sw[e + 1]; p2 = csr_sw[e + 2]; p3 = csr_sw[e + 3];
        ax0 = fmaf(blo(hA), w0, ax0); ay0 = fmaf(bhi(hA), w0, ay0);
        ax1 = fmaf(blo(hB), w1, ax1); ay1 = fmaf(bhi(hB), w1, ay1);
        ax2 = fmaf(blo(hC), w2, ax2); ay2 = fmaf(bhi(hC), w2, ay2);
        ax3 = fmaf(blo(hD), w3, ax3); ay3 = fmaf(bhi(hD), w3, ay3);
        e += 4;
      }
      // drain preloaded group
      {
        uint32_t hA = Hb[(size_t)p0.x * 64 + lane];
        uint32_t hB = Hb[(size_t)p1.x * 64 + lane];
        uint32_t hC = Hb[(size_t)p2.x * 64 + lane];
        uint32_t hD = Hb[(size_t)p3.x * 64 + lane];
        float w0 = __int_as_float(p0.y), w1 = __int_as_float(p1.y);
        float w2 = __int_as_float(p2.y), w3 = __int_as_float(p3.y);
        ax0 = fmaf(blo(hA), w0, ax0); ay0 = fmaf(bhi(hA), w0, ay0);
        ax1 = fmaf(blo(hB), w1, ax1); ay1 = fmaf(bhi(hB), w1, ay1);
        ax2 = fmaf(blo(hC), w2, ax2); ay2 = fmaf(bhi(hC), w2, ay2);
        ax3 = fmaf(blo(hD), w3, ax3); ay3 = fmaf(bhi(hD), w3, ay3);
      }
    }
    for (; e < e1; ++e) {
      int2 p = csr_sw[e];
      uint32_t hA = Hb[(size_t)p.x * 64 + lane];
      float w = __int_as_float(p.y);
      ax0 = fmaf(blo(hA), w, ax0); ay0 = fmaf(bhi(hA), w, ay0);
    }
    float ax = (ax0 + ax1) + (ax2 + ax3);
    float ay = (ay0 + ay1) + (ay2 + ay3);
    a2[(size_t)i * 64 + lane] = make_float2(ax, ay);
    sum0 += ax; sum1 += ay; sq0 += ax * ax; sq1 += ay * ay;
  }
  __shared__ float red[4][128];
  int w = tid >> 6;
  red[w][2 * lane] = sum0; red[w][2 * lane + 1] = sum1;
  __syncthreads();
  if (w == 0) {
    float a = red[0][2 * lane] + red[1][2 * lane] + red[2][2 * lane] + red[3][2 * lane];
    float b = red[0][2 * lane + 1] + red[1][2 * lane + 1] + red[2][2 * lane + 1] + red[3][2 * lane + 1];
    atomicAdd(&stats[2 * lane], a);
    atomicAdd(&stats[2 * lane + 1], b);
  }
  __syncthreads();
  red[w][2 * lane] = sq0; red[w][2 * lane + 1] = sq1;
  __syncthreads();
  if (w == 0) {
    float a = red[0][2 * lane] + red[1][2 * lane] + red[2][2 * lane] + red[3][2 * lane];
    float b = red[0][2 * lane + 1] + red[1][2 * lane + 1] + red[2][2 * lane + 1] + red[3][2 * lane + 1];
    atomicAdd(&stats[128 + 2 * lane], a);
    atomicAdd(&stats[128 + 2 * lane + 1], b);
  }
}

// ---------------- es/ed for GAT ----------------
__global__ __launch_bounds__(256) void compute_esed(const uint32_t* __restrict__ Hb,
                                                    const float* __restrict__ asrc,
                                                    const float* __restrict__ adst,
                                                    float* __restrict__ es, float* __restrict__ ed) {
  int lane = threadIdx.x & 63;
  int gwave = (blockIdx.x * 256 + threadIdx.x) >> 6;
  if (gwave >= N_NODES) return;
  float2 av = ((const float2*)asrc)[lane];
  float2 dv = ((const float2*)adst)[lane];
  uint32_t hv = Hb[(size_t)gwave * 64 + lane];
  float hx = blo(hv), hy = bhi(hv);
  float e_s = hx * av.x + hy * av.y;
  float e_d = hx * dv.x + hy * dv.y;
  for (int off = 32; off; off >>= 1) {
    e_s += __shfl_down(e_s, off);
    e_d += __shfl_down(e_d, off);
  }
  if (lane == 0) { es[gwave] = e_s; ed[gwave] = e_d; }
}

// overwrite csr_sw.y with es[src]
__global__ void gat_pack_kernel(int2* __restrict__ sw, const float* __restrict__ es) {
  int e = blockIdx.x * 256 + threadIdx.x;
  if (e < N_EDGES) {
    int2 v = sw[e];
    v.y = __float_as_int(es[v.x]);
    sw[e] = v;
  }
}

// ---------------- GAT aggregation (no-max softmax, bf16 rows, pipelined) + BN stats ----------------
__global__ __launch_bounds__(256) void gat_agg(const uint32_t* __restrict__ Hb,
                                               const int* __restrict__ rowstart,
                                               const int2* __restrict__ gpack,
                                               const float* __restrict__ es,
                                               const float* __restrict__ ed,
                                               float* __restrict__ agg,
                                               float* __restrict__ stats) {
  int tid = threadIdx.x;
  int lane = tid & 63;
  int gwave = (blockIdx.x * 256 + tid) >> 6;
  int nwaves = (gridDim.x * 256) >> 6;
  float2* a2 = (float2*)agg;
  float sum0 = 0, sum1 = 0, sq0 = 0, sq1 = 0;
  for (int i = gwave; i < N_NODES; i += nwaves) {
    float edi = ed[i];
    float esi = es[i];
    int e0 = rowstart[i], e1 = rowstart[i + 1];
    float wself = __expf(leaky(esi + edi));
    float wsum = (lane == 0) ? wself : 0.f;
    for (int e = e0 + lane; e < e1; e += 64)
      wsum += __expf(leaky(__int_as_float(gpack[e].y) + edi));
    for (int off = 32; off; off >>= 1) wsum += __shfl_xor(wsum, off);
    float inv = 1.f / (wsum + 1e-16f);

    uint32_t hsv = Hb[(size_t)i * 64 + lane];
    float wS = wself * inv;
    float ax0 = blo(hsv) * wS, ay0 = bhi(hsv) * wS;
    float ax1 = 0.f, ay1 = 0.f, ax2 = 0.f, ay2 = 0.f, ax3 = 0.f, ay3 = 0.f;
    int e = e0;
    if (e + 4 <= e1) {
      int2 p0 = gpack[e], p1 = gpack[e + 1], p2 = gpack[e + 2], p3 = gpack[e + 3];
      float w0 = __expf(leaky(__int_as_float(p0.y) + edi)) * inv;
      float w1 = __expf(leaky(__int_as_float(p1.y) + edi)) * inv;
      float w2 = __expf(leaky(__int_as_float(p2.y) + edi)) * inv;
      float w3 = __expf(leaky(__int_as_float(p3.y) + edi)) * inv;
      e += 4;
      while (e + 4 <= e1) {
        uint32_t hA = Hb[(size_t)p0.x * 64 + lane];
        uint32_t hB = Hb[(size_t)p1.x * 64 + lane];
        uint32_t hC = Hb[(size_t)p2.x * 64 + lane];
        uint32_t hD = Hb[(size_t)p3.x * 64 + lane];
        float cw0 = w0, cw1 = w1, cw2 = w2, cw3 = w3;
        p0 = gpack[e]; p1 = gpack[e + 1]; p2 = gpack[e + 2]; p3 = gpack[e + 3];
        w0 = __expf(leaky(__int_as_float(p0.y) + edi)) * inv;
        w1 = __expf(leaky(__int_as_float(p1.y) + edi)) * inv;
        w2 = __expf(leaky(__int_as_float(p2.y) + edi)) * inv;
        w3 = __expf(leaky(__int_as_float(p3.y) + edi)) * inv;
        ax0 = fmaf(blo(hA), cw0, ax0); ay0 = fmaf(bhi(hA), cw0, ay0);
        ax1 = fmaf(blo(hB), cw1, ax1); ay1 = fmaf(bhi(hB), cw1, ay1);
        ax2 = fmaf(blo(hC), cw2, ax2); ay2 = fmaf(bhi(hC), cw2, ay2);
        ax3 = fmaf(blo(hD), cw3, ax3); ay3 = fmaf(bhi(hD), cw3, ay3);
        e += 4;
      }
      {
        uint32_t hA = Hb[(size_t)p0.x * 64 + lane];
        uint32_t hB = Hb[(size_t)p1.x * 64 + lane];
        uint32_t hC = Hb[(size_t)p2.x * 64 + lane];
        uint32_t hD = Hb[(size_t)p3.x * 64 + lane];
        ax0 = fmaf(blo(hA), w0, ax0); ay0 = fmaf(bhi(hA), w0, ay0);
        ax1 = fmaf(blo(hB), w1, ax1); ay1 = fmaf(bhi(hB), w1, ay1);
        ax2 = fmaf(blo(hC), w2, ax2); ay2 = fmaf(bhi(hC), w2, ay2);
        ax3 = fmaf(blo(hD), w3, ax3); ay3 = fmaf(bhi(hD), w3, ay3);
      }
    }
    for (; e < e1; ++e) {
      int2 p = gpack[e];
      float w = __expf(leaky(__int_as_float(p.y) + edi)) * inv;
      uint32_t hA = Hb[(size_t)p.x * 64 + lane];
      ax0 = fmaf(blo(hA), w, ax0); ay0 = fmaf(bhi(hA), w, ay0);
    }
    float ax = (ax0 + ax1) + (ax2 + ax3);
    float ay = (ay0 + ay1) + (ay2 + ay3);
    a2[(size_t)i * 64 + lane] = make_float2(ax, ay);
    sum0 += ax; sum1 += ay; sq0 += ax * ax; sq1 += ay * ay;
  }
  __shared__ float red[4][128];
  int w = tid >> 6;
  red[w][2 * lane] = sum0; red[w][2 * lane + 1] = sum1;
  __syncthreads();
  if (w == 0) {
    float a = red[0][2 * lane] + red[1][2 * lane] + red[2][2 * lane] + red[3][2 * lane];
    float b = red[0][2 * lane + 1] + red[1][2 * lane + 1] + red[2][2 * lane + 1] + red[3][2 * lane + 1];
    atomicAdd(&stats[2 * lane], a);
    atomicAdd(&stats[2 * lane + 1], b);
  }
  __syncthreads();
  red[w][2 * lane] = sq0; red[w][2 * lane + 1] = sq1;
  __syncthreads();
  if (w == 0) {
    float a = red[0][2 * lane] + red[1][2 * lane] + red[2][2 * lane] + red[3][2 * lane];
    float b = red[0][2 * lane + 1] + red[1][2 * lane + 1] + red[2][2 * lane + 1] + red[3][2 * lane + 1];
    atomicAdd(&stats[128 + 2 * lane], a);
    atomicAdd(&stats[128 + 2 * lane + 1], b);
  }
}

// ---------------- BN(train) + ReLU + residual (f32 out + bf16 copy for next GEMM) ----------------
__global__ void bn_relu_res(const float* __restrict__ agg, const float* __restrict__ xin,
                            const float* __restrict__ stats, const float* __restrict__ gamma,
                            const float* __restrict__ beta, float* __restrict__ xout,
                            uint32_t* __restrict__ xb) {
  size_t idx = (size_t)blockIdx.x * 256 + threadIdx.x;  // float2 index
  if (idx >= (size_t)N_NODES * 64) return;
  int c = ((int)(idx & 63)) * 2;
  const float n_inv = 1.f / (float)N_NODES;
  float m0 = stats[c] * n_inv, m1 = stats[c + 1] * n_inv;
  float v0 = stats[128 + c] * n_inv - m0 * m0;
  float v1 = stats[128 + c + 1] * n_inv - m1 * m1;
  float s0 = gamma[c] * rsqrtf(v0 + BN_EPS);
  float s1 = gamma[c + 1] * rsqrtf(v1 + BN_EPS);
  float b0 = beta[c] - m0 * s0;
  float b1 = beta[c + 1] - m1 * s1;
  float2 a = ((const float2*)agg)[idx];
  float2 xi = ((const float2*)xin)[idx];
  float r0 = fmaxf(fmaf(a.x, s0, b0), 0.f) + xi.x;
  float r1 = fmaxf(fmaf(a.y, s1, b1), 0.f) + xi.y;
  ((float2*)xout)[idx] = make_float2(r0, r1);
  if (xb) xb[idx] = pack2(r0, r1);
}

// ---------------- pooling ----------------
__global__ void graph_starts(const int* __restrict__ batch, int* __restrict__ gstart) {
  int n = blockIdx.x * 256 + threadIdx.x;
  if (n >= N_NODES) return;
  int b = batch[n];
  int bp = (n == 0) ? -1 : batch[n - 1];
  for (int g = bp + 1; g <= b; ++g) gstart[g] = n;
  if (n == N_NODES - 1) {
    for (int g = b + 1; g <= BG; ++g) gstart[g] = N_NODES;
  }
}

__global__ __launch_bounds__(256) void pool_kernel(const float* __restrict__ x,
                                                   const int* __restrict__ gstart,
                                                   float* __restrict__ pooled) {
  int g = blockIdx.x;
  int c = threadIdx.x & 127;
  int half = threadIdx.x >> 7;
  int s = gstart[g], e = gstart[g + 1];
  float acc = 0.f;
  for (int n = s + half; n < e; n += 2) acc += x[(size_t)n * 128 + c];
  __shared__ float red[256];
  red[threadIdx.x] = acc;
  __syncthreads();
  if (half == 0) {
    float v = red[c] + red[128 + c];
    int cnt = e - s;
    pooled[(size_t)g * 128 + c] = v / fmaxf((float)cnt, 1.f);
  }
}

// ---------------- f32 GEMM (MLP head only) ----------------
template <int RELU, int BIAS>
__global__ __launch_bounds__(256) void gemm_f32(const float* __restrict__ A,
                                                const float* __restrict__ W,
                                                const float* __restrict__ bias,
                                                float* __restrict__ Cmat,
                                                int M, int K, int N) {
  __shared__ float As[32][128];
  __shared__ float Bs[32][128];
  int tid = threadIdx.x;
  int row0 = blockIdx.x * 128, col0 = blockIdx.y * 128;
  int tx = tid & 15, ty = tid >> 4;
  float acc[8][8];
#pragma unroll
  for (int i = 0; i < 8; ++i)
#pragma unroll
    for (int j = 0; j < 8; ++j) acc[i][j] = 0.f;

  for (int k0 = 0; k0 < K; k0 += 32) {
    {
      int r = tid >> 1;
      int kseg = (tid & 1) * 16;
      bool valid = (row0 + r) < M;
      const float* ap = A + (size_t)(row0 + r) * K + k0 + kseg;
#pragma unroll
      for (int q = 0; q < 4; ++q) {
        float4 v;
        if (valid) v = *(const float4*)(ap + q * 4);
        else { v.x = v.y = v.z = v.w = 0.f; }
        As[kseg + q * 4 + 0][r] = v.x;
        As[kseg + q * 4 + 1][r] = v.y;
        As[kseg + q * 4 + 2][r] = v.z;
        As[kseg + q * 4 + 3][r] = v.w;
      }
    }
    {
      int kk = tid >> 3;
      int seg = (tid & 7) * 16;
      const float* wp = W + (size_t)(k0 + kk) * N + col0 + seg;
#pragma unroll
      for (int q = 0; q < 4; ++q)
        *(float4*)&Bs[kk][seg + q * 4] = *(const float4*)(wp + q * 4);
    }
    __syncthreads();
#pragma unroll
    for (int kk = 0; kk < 32; ++kk) {
      float4 a0 = *(const float4*)&As[kk][ty * 4];
      float4 a1 = *(const float4*)&As[kk][64 + ty * 4];
      float4 b0 = *(const float4*)&Bs[kk][tx * 4];
      float4 b1 = *(const float4*)&Bs[kk][64 + tx * 4];
      float av[8] = {a0.x, a0.y, a0.z, a0.w, a1.x, a1.y, a1.z, a1.w};
      float bv[8] = {b0.x, b0.y, b0.z, b0.w, b1.x, b1.y, b1.z, b1.w};
#pragma unroll
      for (int i = 0; i < 8; ++i)
#pragma unroll
        for (int j = 0; j < 8; ++j) acc[i][j] = fmaf(av[i], bv[j], acc[i][j]);
    }
    __syncthreads();
  }
#pragma unroll
  for (int i = 0; i < 8; ++i) {
    int r = row0 + ((i < 4) ? (ty * 4 + i) : (64 + ty * 4 + i - 4));
    if (r >= M) continue;
#pragma unroll
    for (int j = 0; j < 8; ++j) {
      int c = col0 + ((j < 4) ? (tx * 4 + j) : (64 + tx * 4 + j - 4));
      float v = acc[i][j];
      if (BIAS) v += bias[c];
      if (RELU) v = fmaxf(v, 0.f);
      Cmat[(size_t)r * N + c] = v;
    }
  }
}

// ---------------- host launch ----------------
extern "C" void kernel_launch(void* const* d_in, const int* in_sizes, int n_in,
                              void* d_out, int out_size, void* d_ws, size_t ws_size,
                              hipStream_t stream) {
  const float* x_in  = (const float*)d_in[0];
  const int*   eidx  = (const int*)d_in[1];
  const int*   batch = (const int*)d_in[2];
  const float* W1 = (const float*)d_in[3];
  const float* g1 = (const float*)d_in[5];
  const float* be1 = (const float*)d_in[6];
  const float* W2 = (const float*)d_in[7];
  const float* g2 = (const float*)d_in[9];
  const float* be2 = (const float*)d_in[10];
  const float* W3 = (const float*)d_in[11];
  const float* g3 = (const float*)d_in[13];
  const float* be3 = (const float*)d_in[14];
  const float* Wa = (const float*)d_in[15];
  const float* asrc = (const float*)d_in[16];
  const float* adst = (const float*)d_in[17];
  const float* ga = (const float*)d_in[19];
  const float* bea = (const float*)d_in[20];
  const float* Wh1 = (const float*)d_in[21];
  const float* bh1 = (const float*)d_in[22];
  const float* Wm0 = (const float*)d_in[23];
  const float* bm0 = (const float*)d_in[24];
  const float* Wm1 = (const float*)d_in[25];
  const float* bm1 = (const float*)d_in[26];
  const float* Wo = (const float*)d_in[27];
  const float* bo = (const float*)d_in[28];

  const int* src = eidx;
  const int* dst = eidx + N_EDGES;

  char* p = (char*)d_ws;
  auto alloc = [&](size_t bytes) {
    char* r = p;
    p += (bytes + 255) & ~(size_t)255;
    return r;
  };
  uint32_t* Hb     = (uint32_t*)alloc((size_t)N_NODES * 64 * 4);   // bf16-pair h
  uint32_t* xb     = (uint32_t*)alloc((size_t)N_NODES * 64 * 4);   // bf16-pair x (GEMM A)
  float* agg       = (float*)alloc((size_t)N_NODES * CCH * 4);
  float* xbuf      = (float*)alloc((size_t)N_NODES * CCH * 4);
  int2*  csr_sw    = (int2*)alloc((size_t)N_EDGES * 8);
  int*   rowstart  = (int*)alloc((size_t)(N_NODES + 1) * 4);
  int*   indeg     = (int*)alloc((size_t)2 * N_NODES * 4);
  int*   cursor    = indeg + N_NODES;
  float* dinv      = (float*)alloc((size_t)N_NODES * 4);
  float* es        = (float*)alloc((size_t)N_NODES * 4);
  float* ed        = (float*)alloc((size_t)N_NODES * 4);
  int*   chunksum  = (int*)alloc(128 * 4);
  float* stats     = (float*)alloc(4 * 256 * 4);
  int*   gstart    = (int*)alloc((BG + 1) * 4);
  float* pooled    = (float*)alloc((size_t)BG * CCH * 4);
  float* m1        = (float*)alloc((size_t)BG * NHID * 4);
  float* m2        = (float*)alloc((size_t)BG * NHID * 4);
  unsigned short* Wp1 = (unsigned short*)alloc(2048 * 8 * 2);
  unsigned short* Wp2 = (unsigned short*)alloc(2048 * 8 * 2);
  unsigned short* Wp3 = (unsigned short*)alloc(2048 * 8 * 2);
  unsigned short* Wp4 = (unsigned short*)alloc(2048 * 8 * 2);

  hipMemsetAsync(indeg, 0, (size_t)2 * N_NODES * 4, stream);
  hipMemsetAsync(stats, 0, 4 * 256 * 4, stream);

  // CSR build
  hist_kernel<<<(N_EDGES + 255) / 256, 256, 0, stream>>>(dst, indeg);
  scan_chunks<<<98, 256, 0, stream>>>(indeg, rowstart, chunksum);
  scan_sums<<<1, 128, 0, stream>>>(chunksum, 98);
  scan_add<<<(N_NODES + 256) / 256, 256, 0, stream>>>(rowstart, chunksum);
  compute_dinv<<<(N_NODES + 255) / 256, 256, 0, stream>>>(indeg, dinv);
  scatter_edges<<<(N_EDGES + 255) / 256, 256, 0, stream>>>(src, dst, rowstart, cursor, dinv, csr_sw);

  // bf16 prep
  const int el2_blocks = (N_NODES * 64 + 255) / 256;
  cast_bf16_kernel<<<el2_blocks, 256, 0, stream>>>((const float2*)x_in, xb);
  pack_w_kernel<<<8, 256, 0, stream>>>(W1, Wp1);
  pack_w_kernel<<<8, 256, 0, stream>>>(W2, Wp2);
  pack_w_kernel<<<8, 256, 0, stream>>>(W3, Wp3);
  pack_w_kernel<<<8, 256, 0, stream>>>(Wa, Wp4);

  const int gemm_blocks_m = (N_NODES + 127) / 128;  // 782
  const int AGG_BLOCKS = 2048;                      // 8192 waves

  const float* xcur = x_in;
  const unsigned short* Wps[3] = {Wp1, Wp2, Wp3};
  const float* gs[3] = {g1, g2, g3};
  const float* bes[3] = {be1, be2, be3};
  for (int l = 0; l < 3; ++l) {
    gemm_mfma<<<gemm_blocks_m, 256, 0, stream>>>(xb, Wps[l], Hb, N_NODES);
    gcn_agg<<<AGG_BLOCKS, 256, 0, stream>>>(Hb, rowstart, csr_sw, dinv, agg, stats + l * 256);
    bn_relu_res<<<el2_blocks, 256, 0, stream>>>(agg, xcur, stats + l * 256, gs[l], bes[l], xbuf, xb);
    xcur = xbuf;
  }

  // GAT layer
  gemm_mfma<<<gemm_blocks_m, 256, 0, stream>>>(xb, Wp4, Hb, N_NODES);
  compute_esed<<<(N_NODES + 3) / 4, 256, 0, stream>>>(Hb, asrc, adst, es, ed);
  gat_pack_kernel<<<(N_EDGES + 255) / 256, 256, 0, stream>>>(csr_sw, es);
  gat_agg<<<AGG_BLOCKS, 256, 0, stream>>>(Hb, rowstart, csr_sw, es, ed, agg, stats + 3 * 256);
  bn_relu_res<<<el2_blocks, 256, 0, stream>>>(agg, xcur, stats + 3 * 256, ga, bea, xbuf, (uint32_t*)nullptr);

  // pooling
  graph_starts<<<(N_NODES + 255) / 256, 256, 0, stream>>>(batch, gstart);
  pool_kernel<<<BG, 256, 0, stream>>>(xbuf, gstart, pooled);

  // MLP head (f32)
  gemm_f32<1, 1><<<dim3(4, 4), 256, 0, stream>>>(pooled, Wh1, bh1, m1, BG, CCH, NHID);
  gemm_f32<1, 1><<<dim3(4, 4), 256, 0, stream>>>(m1, Wm0, bm0, m2, BG, NHID, NHID);
  gemm_f32<1, 1><<<dim3(4, 4), 256, 0, stream>>>(m2, Wm1, bm1, m1, BG, NHID, NHID);
  gemm_f32<0, 1><<<dim3(4, 2), 256, 0, stream>>>(m1, Wo, bo, (float*)d_out, BG, NHID, NOUT);
}

// Round 4
// 1182.149 us; speedup vs baseline: 1.5935x; 1.1122x over previous
//
#include <hip/hip_runtime.h>

// Problem constants (match reference)
#define N_NODES 100000
#define N_EDGES 1600000
#define CCH     128
#define BG      512
#define NHID    512
#define NOUT    256
#define BN_EPS  1e-5f

typedef __attribute__((ext_vector_type(8))) short s16x8;
typedef __attribute__((ext_vector_type(4))) float f32x4;

static __device__ __forceinline__ float leaky(float x) { return x > 0.f ? x : 0.2f * x; }
// bf16 round-to-nearest-even, returns low 16 bits
static __device__ __forceinline__ uint32_t bfr16(float x) {
  uint32_t u = __float_as_uint(x);
  u += 0x7fffu + ((u >> 16) & 1u);
  return u >> 16;
}
static __device__ __forceinline__ uint32_t pack2(float a, float b) {
  return bfr16(a) | (bfr16(b) << 16);
}
static __device__ __forceinline__ float blo(uint32_t u) { return __uint_as_float(u << 16); }
static __device__ __forceinline__ float bhi(uint32_t u) { return __uint_as_float(u & 0xffff0000u); }

// ---------------- graph prep ----------------
__global__ void hist_kernel(const int* __restrict__ dst, int* __restrict__ indeg) {
  int e = blockIdx.x * 256 + threadIdx.x;
  if (e < N_EDGES) atomicAdd(&indeg[dst[e]], 1);
}

__global__ __launch_bounds__(256) void scan_chunks(const int* __restrict__ indeg,
                                                   int* __restrict__ rowstart,
                                                   int* __restrict__ chunksum) {
  int tid = threadIdx.x;
  int base = blockIdx.x * 1024 + tid * 4;
  int4 v;
  if (base + 3 < N_NODES) {
    v = *(const int4*)(indeg + base);
  } else {
    v.x = (base + 0 < N_NODES) ? indeg[base + 0] : 0;
    v.y = (base + 1 < N_NODES) ? indeg[base + 1] : 0;
    v.z = (base + 2 < N_NODES) ? indeg[base + 2] : 0;
    v.w = (base + 3 < N_NODES) ? indeg[base + 3] : 0;
  }
  int s = v.x + v.y + v.z + v.w;
  __shared__ int ss[256];
  ss[tid] = s;
  __syncthreads();
  for (int off = 1; off < 256; off <<= 1) {
    int t = (tid >= off) ? ss[tid - off] : 0;
    __syncthreads();
    ss[tid] += t;
    __syncthreads();
  }
  int excl = ss[tid] - s;
  if (base + 0 < N_NODES) rowstart[base + 0] = excl;
  if (base + 1 < N_NODES) rowstart[base + 1] = excl + v.x;
  if (base + 2 < N_NODES) rowstart[base + 2] = excl + v.x + v.y;
  if (base + 3 < N_NODES) rowstart[base + 3] = excl + v.x + v.y + v.z;
  if (tid == 255) chunksum[blockIdx.x] = ss[255];
}

__global__ void scan_sums(int* __restrict__ chunksum, int nch) {
  __shared__ int ss[128];
  int tid = threadIdx.x;
  int v = (tid < nch) ? chunksum[tid] : 0;
  ss[tid] = v;
  __syncthreads();
  for (int off = 1; off < 128; off <<= 1) {
    int t = (tid >= off) ? ss[tid - off] : 0;
    __syncthreads();
    ss[tid] += t;
    __syncthreads();
  }
  if (tid < nch) chunksum[tid] = ss[tid] - v;  // exclusive
}

__global__ void scan_add(int* __restrict__ rowstart, const int* __restrict__ chunksum) {
  int i = blockIdx.x * 256 + threadIdx.x;
  if (i < N_NODES)      rowstart[i] += chunksum[i >> 10];
  else if (i == N_NODES) rowstart[N_NODES] = N_EDGES;
}

__global__ void compute_dinv(const int* __restrict__ indeg, float* __restrict__ dinv) {
  int i = blockIdx.x * 256 + threadIdx.x;
  if (i < N_NODES) dinv[i] = rsqrtf((float)(indeg[i] + 1));
}

__global__ void scatter_edges(const int* __restrict__ src, const int* __restrict__ dst,
                              const int* __restrict__ rowstart, int* __restrict__ cursor,
                              const float* __restrict__ dinv, int2* __restrict__ csr_sw) {
  int e = blockIdx.x * 256 + threadIdx.x;
  if (e < N_EDGES) {
    int d = dst[e];
    int s = src[e];
    int p = rowstart[d] + atomicAdd(&cursor[d], 1);
    float w = dinv[s] * dinv[d];
    csr_sw[p] = make_int2(s, __float_as_int(w));
  }
}

// ---------------- bf16 helpers ----------------
__global__ void cast_bf16_kernel(const float2* __restrict__ x2, uint32_t* __restrict__ xb) {
  size_t idx = (size_t)blockIdx.x * 256 + threadIdx.x;
  if (idx >= (size_t)N_NODES * 64) return;
  float2 v = x2[idx];
  xb[idx] = pack2(v.x, v.y);
}

// pack W[128][128] f32 into MFMA b-frag order
__global__ void pack_w_kernel(const float* __restrict__ W, unsigned short* __restrict__ Wp) {
  int t = blockIdx.x * 256 + threadIdx.x;
  if (t >= 2048) return;
  int lane = t & 63;
  int ks = (t >> 6) & 3;
  int nt = t >> 8;
  int c = nt * 16 + (lane & 15);
  int kb = ks * 32 + (lane >> 4) * 8;
#pragma unroll
  for (int i = 0; i < 8; ++i)
    Wp[(size_t)t * 8 + i] = (unsigned short)bfr16(W[(size_t)(kb + i) * 128 + c]);
}

// ---------------- MFMA conv GEMM ----------------
__global__ __launch_bounds__(256) void gemm_mfma(const uint32_t* __restrict__ Ab,
                                                 const unsigned short* __restrict__ Wp,
                                                 uint32_t* __restrict__ Hb,
                                                 int M) {
  int wave = threadIdx.x >> 6, lane = threadIdx.x & 63;
  int row0 = blockIdx.x * 128 + wave * 32;
  const unsigned short* A16 = (const unsigned short*)Ab;

  f32x4 acc[2][8];
#pragma unroll
  for (int mt = 0; mt < 2; ++mt)
#pragma unroll
    for (int nt = 0; nt < 8; ++nt) acc[mt][nt] = (f32x4){0.f, 0.f, 0.f, 0.f};

  s16x8 a[2][4];
  int r = lane & 15, ko = (lane >> 4) * 8;
#pragma unroll
  for (int mt = 0; mt < 2; ++mt) {
    int row = row0 + mt * 16 + r;
    bool v = row < M;
    const unsigned short* ap = A16 + (size_t)row * 128 + ko;
#pragma unroll
    for (int ks = 0; ks < 4; ++ks) {
      s16x8 af = {0, 0, 0, 0, 0, 0, 0, 0};
      if (v) af = *(const s16x8*)(ap + ks * 32);
      a[mt][ks] = af;
    }
  }
#pragma unroll
  for (int ks = 0; ks < 4; ++ks) {
#pragma unroll
    for (int nt = 0; nt < 8; ++nt) {
      s16x8 b = *(const s16x8*)(Wp + ((size_t)(nt * 4 + ks) * 64 + lane) * 8);
      acc[0][nt] = __builtin_amdgcn_mfma_f32_16x16x32_bf16(a[0][ks], b, acc[0][nt], 0, 0, 0);
      acc[1][nt] = __builtin_amdgcn_mfma_f32_16x16x32_bf16(a[1][ks], b, acc[1][nt], 0, 0, 0);
    }
  }
#pragma unroll
  for (int mt = 0; mt < 2; ++mt) {
#pragma unroll
    for (int nt = 0; nt < 8; ++nt) {
#pragma unroll
      for (int reg = 0; reg < 4; ++reg) {
        float v0 = acc[mt][nt][reg];
        float v1 = __shfl_xor(v0, 1);
        int row = row0 + mt * 16 + (lane >> 4) * 4 + reg;
        int col = nt * 16 + (lane & 15);
        if (!(lane & 1) && row < M)
          Hb[(size_t)row * 64 + (col >> 1)] = pack2(v0, v1);
      }
    }
  }
}

// ---------------- GCN aggregation: 2 nodes per wave (32-lane halves) + BN stats ----------------
__global__ __launch_bounds__(256) void gcn_agg(const uint2* __restrict__ Hb2,
                                               const int* __restrict__ rowstart,
                                               const int2* __restrict__ csr_sw,
                                               const float* __restrict__ dinv,
                                               float4* __restrict__ agg4,
                                               float* __restrict__ stats) {
  int tid = threadIdx.x;
  int lane = tid & 63;
  int hl = lane & 31;
  int half = lane >> 5;
  int gw = (blockIdx.x * 256 + tid) >> 6;
  int nw = (gridDim.x * 256) >> 6;
  float s0 = 0, s1 = 0, s2 = 0, s3 = 0, q0 = 0, q1 = 0, q2 = 0, q3 = 0;
  for (int pi = gw; pi < N_NODES / 2; pi += nw) {
    int n = 2 * pi + half;
    int e0 = rowstart[n], e1 = rowstart[n + 1];
    int len = e1 - e0;
    int G = (len + 3) >> 2;
    int Gmax = max(G, __shfl_xor(G, 32));
    int ecl = (len > 0) ? (e1 - 1) : 0;
    float di = dinv[n];
    uint2 hs = Hb2[(size_t)n * 32 + hl];
    float ws = di * di;
    float c0 = blo(hs.x) * ws, c1 = bhi(hs.x) * ws;
    float c2 = blo(hs.y) * ws, c3 = bhi(hs.y) * ws;
    int sI0, sI1, sI2, sI3;
    float w0, w1, w2, w3;
    {
      int e = e0;
      int2 pa = csr_sw[e < e1 ? e : ecl];
      int2 pb = csr_sw[e + 1 < e1 ? e + 1 : ecl];
      int2 pc = csr_sw[e + 2 < e1 ? e + 2 : ecl];
      int2 pd = csr_sw[e + 3 < e1 ? e + 3 : ecl];
      sI0 = pa.x; w0 = (e < e1) ? __int_as_float(pa.y) : 0.f;
      sI1 = pb.x; w1 = (e + 1 < e1) ? __int_as_float(pb.y) : 0.f;
      sI2 = pc.x; w2 = (e + 2 < e1) ? __int_as_float(pc.y) : 0.f;
      sI3 = pd.x; w3 = (e + 3 < e1) ? __int_as_float(pd.y) : 0.f;
    }
    for (int g = 0; g < Gmax; ++g) {
      uint2 r0 = Hb2[(size_t)sI0 * 32 + hl];
      uint2 r1 = Hb2[(size_t)sI1 * 32 + hl];
      uint2 r2 = Hb2[(size_t)sI2 * 32 + hl];
      uint2 r3 = Hb2[(size_t)sI3 * 32 + hl];
      float cw0 = w0, cw1 = w1, cw2 = w2, cw3 = w3;
      int e = e0 + (g + 1) * 4;
      int2 pa = csr_sw[e < e1 ? e : ecl];
      int2 pb = csr_sw[e + 1 < e1 ? e + 1 : ecl];
      int2 pc = csr_sw[e + 2 < e1 ? e + 2 : ecl];
      int2 pd = csr_sw[e + 3 < e1 ? e + 3 : ecl];
      sI0 = pa.x; w0 = (e < e1) ? __int_as_float(pa.y) : 0.f;
      sI1 = pb.x; w1 = (e + 1 < e1) ? __int_as_float(pb.y) : 0.f;
      sI2 = pc.x; w2 = (e + 2 < e1) ? __int_as_float(pc.y) : 0.f;
      sI3 = pd.x; w3 = (e + 3 < e1) ? __int_as_float(pd.y) : 0.f;
      c0 = fmaf(blo(r0.x), cw0, c0); c1 = fmaf(bhi(r0.x), cw0, c1);
      c2 = fmaf(blo(r0.y), cw0, c2); c3 = fmaf(bhi(r0.y), cw0, c3);
      c0 = fmaf(blo(r1.x), cw1, c0); c1 = fmaf(bhi(r1.x), cw1, c1);
      c2 = fmaf(blo(r1.y), cw1, c2); c3 = fmaf(bhi(r1.y), cw1, c3);
      c0 = fmaf(blo(r2.x), cw2, c0); c1 = fmaf(bhi(r2.x), cw2, c1);
      c2 = fmaf(blo(r2.y), cw2, c2); c3 = fmaf(bhi(r2.y), cw2, c3);
      c0 = fmaf(blo(r3.x), cw3, c0); c1 = fmaf(bhi(r3.x), cw3, c1);
      c2 = fmaf(blo(r3.y), cw3, c2); c3 = fmaf(bhi(r3.y), cw3, c3);
    }
    agg4[(size_t)n * 32 + hl] = make_float4(c0, c1, c2, c3);
    s0 += c0; s1 += c1; s2 += c2; s3 += c3;
    q0 += c0 * c0; q1 += c1 * c1; q2 += c2 * c2; q3 += c3 * c3;
  }
  // cross-half combine (both halves hold same channels 4hl..4hl+3)
  s0 += __shfl_xor(s0, 32); s1 += __shfl_xor(s1, 32);
  s2 += __shfl_xor(s2, 32); s3 += __shfl_xor(s3, 32);
  q0 += __shfl_xor(q0, 32); q1 += __shfl_xor(q1, 32);
  q2 += __shfl_xor(q2, 32); q3 += __shfl_xor(q3, 32);
  __shared__ float red[4][128];
  int w = tid >> 6;
  if (half == 0) {
    red[w][4 * hl + 0] = s0; red[w][4 * hl + 1] = s1;
    red[w][4 * hl + 2] = s2; red[w][4 * hl + 3] = s3;
  }
  __syncthreads();
  if (w == 0) {
    float a = red[0][2 * lane] + red[1][2 * lane] + red[2][2 * lane] + red[3][2 * lane];
    float b = red[0][2 * lane + 1] + red[1][2 * lane + 1] + red[2][2 * lane + 1] + red[3][2 * lane + 1];
    atomicAdd(&stats[2 * lane], a);
    atomicAdd(&stats[2 * lane + 1], b);
  }
  __syncthreads();
  if (half == 0) {
    red[w][4 * hl + 0] = q0; red[w][4 * hl + 1] = q1;
    red[w][4 * hl + 2] = q2; red[w][4 * hl + 3] = q3;
  }
  __syncthreads();
  if (w == 0) {
    float a = red[0][2 * lane] + red[1][2 * lane] + red[2][2 * lane] + red[3][2 * lane];
    float b = red[0][2 * lane + 1] + red[1][2 * lane + 1] + red[2][2 * lane + 1] + red[3][2 * lane + 1];
    atomicAdd(&stats[128 + 2 * lane], a);
    atomicAdd(&stats[128 + 2 * lane + 1], b);
  }
}

// ---------------- es/ed for GAT ----------------
__global__ __launch_bounds__(256) void compute_esed(const uint32_t* __restrict__ Hb,
                                                    const float* __restrict__ asrc,
                                                    const float* __restrict__ adst,
                                                    float* __restrict__ es, float* __restrict__ ed) {
  int lane = threadIdx.x & 63;
  int gwave = (blockIdx.x * 256 + threadIdx.x) >> 6;
  if (gwave >= N_NODES) return;
  float2 av = ((const float2*)asrc)[lane];
  float2 dv = ((const float2*)adst)[lane];
  uint32_t hv = Hb[(size_t)gwave * 64 + lane];
  float hx = blo(hv), hy = bhi(hv);
  float e_s = hx * av.x + hy * av.y;
  float e_d = hx * dv.x + hy * dv.y;
  for (int off = 32; off; off >>= 1) {
    e_s += __shfl_down(e_s, off);
    e_d += __shfl_down(e_d, off);
  }
  if (lane == 0) { es[gwave] = e_s; ed[gwave] = e_d; }
}

__global__ void gat_pack_kernel(int2* __restrict__ sw, const float* __restrict__ es) {
  int e = blockIdx.x * 256 + threadIdx.x;
  if (e < N_EDGES) {
    int2 v = sw[e];
    v.y = __float_as_int(es[v.x]);
    sw[e] = v;
  }
}

// ---------------- GAT aggregation: 2 nodes per wave + BN stats ----------------
__global__ __launch_bounds__(256) void gat_agg(const uint2* __restrict__ Hb2,
                                               const int* __restrict__ rowstart,
                                               const int2* __restrict__ gpack,
                                               const float* __restrict__ es,
                                               const float* __restrict__ ed,
                                               float4* __restrict__ agg4,
                                               float* __restrict__ stats) {
  int tid = threadIdx.x;
  int lane = tid & 63;
  int hl = lane & 31;
  int half = lane >> 5;
  int gw = (blockIdx.x * 256 + tid) >> 6;
  int nw = (gridDim.x * 256) >> 6;
  float s0 = 0, s1 = 0, s2 = 0, s3 = 0, q0 = 0, q1 = 0, q2 = 0, q3 = 0;
  for (int pi = gw; pi < N_NODES / 2; pi += nw) {
    int n = 2 * pi + half;
    int e0 = rowstart[n], e1 = rowstart[n + 1];
    int len = e1 - e0;
    int G = (len + 3) >> 2;
    int Gmax = max(G, __shfl_xor(G, 32));
    int ecl = (len > 0) ? (e1 - 1) : 0;
    float edi = ed[n], esi = es[n];
    float wself = __expf(leaky(esi + edi));
    // lane-parallel softmax denominator within half
    float wsum = (hl == 0) ? wself : 0.f;
    for (int e = e0 + hl; e < e1; e += 32)
      wsum += __expf(leaky(__int_as_float(gpack[e].y) + edi));
#pragma unroll
    for (int off = 16; off; off >>= 1) wsum += __shfl_xor(wsum, off);
    float inv = 1.f / (wsum + 1e-16f);

    uint2 hs = Hb2[(size_t)n * 32 + hl];
    float wS = wself * inv;
    float c0 = blo(hs.x) * wS, c1 = bhi(hs.x) * wS;
    float c2 = blo(hs.y) * wS, c3 = bhi(hs.y) * wS;
    int sI0, sI1, sI2, sI3;
    float w0, w1, w2, w3;
    {
      int e = e0;
      int2 pa = gpack[e < e1 ? e : ecl];
      int2 pb = gpack[e + 1 < e1 ? e + 1 : ecl];
      int2 pc = gpack[e + 2 < e1 ? e + 2 : ecl];
      int2 pd = gpack[e + 3 < e1 ? e + 3 : ecl];
      sI0 = pa.x; w0 = (e < e1) ? __expf(leaky(__int_as_float(pa.y) + edi)) * inv : 0.f;
      sI1 = pb.x; w1 = (e + 1 < e1) ? __expf(leaky(__int_as_float(pb.y) + edi)) * inv : 0.f;
      sI2 = pc.x; w2 = (e + 2 < e1) ? __expf(leaky(__int_as_float(pc.y) + edi)) * inv : 0.f;
      sI3 = pd.x; w3 = (e + 3 < e1) ? __expf(leaky(__int_as_float(pd.y) + edi)) * inv : 0.f;
    }
    for (int g = 0; g < Gmax; ++g) {
      uint2 r0 = Hb2[(size_t)sI0 * 32 + hl];
      uint2 r1 = Hb2[(size_t)sI1 * 32 + hl];
      uint2 r2 = Hb2[(size_t)sI2 * 32 + hl];
      uint2 r3 = Hb2[(size_t)sI3 * 32 + hl];
      float cw0 = w0, cw1 = w1, cw2 = w2, cw3 = w3;
      int e = e0 + (g + 1) * 4;
      int2 pa = gpack[e < e1 ? e : ecl];
      int2 pb = gpack[e + 1 < e1 ? e + 1 : ecl];
      int2 pc = gpack[e + 2 < e1 ? e + 2 : ecl];
      int2 pd = gpack[e + 3 < e1 ? e + 3 : ecl];
      sI0 = pa.x; w0 = (e < e1) ? __expf(leaky(__int_as_float(pa.y) + edi)) * inv : 0.f;
      sI1 = pb.x; w1 = (e + 1 < e1) ? __expf(leaky(__int_as_float(pb.y) + edi)) * inv : 0.f;
      sI2 = pc.x; w2 = (e + 2 < e1) ? __expf(leaky(__int_as_float(pc.y) + edi)) * inv : 0.f;
      sI3 = pd.x; w3 = (e + 3 < e1) ? __expf(leaky(__int_as_float(pd.y) + edi)) * inv : 0.f;
      c0 = fmaf(blo(r0.x), cw0, c0); c1 = fmaf(bhi(r0.x), cw0, c1);
      c2 = fmaf(blo(r0.y), cw0, c2); c3 = fmaf(bhi(r0.y), cw0, c3);
      c0 = fmaf(blo(r1.x), cw1, c0); c1 = fmaf(bhi(r1.x), cw1, c1);
      c2 = fmaf(blo(r1.y), cw1, c2); c3 = fmaf(bhi(r1.y), cw1, c3);
      c0 = fmaf(blo(r2.x), cw2, c0); c1 = fmaf(bhi(r2.x), cw2, c1);
      c2 = fmaf(blo(r2.y), cw2, c2); c3 = fmaf(bhi(r2.y), cw2, c3);
      c0 = fmaf(blo(r3.x), cw3, c0); c1 = fmaf(bhi(r3.x), cw3, c1);
      c2 = fmaf(blo(r3.y), cw3, c2); c3 = fmaf(bhi(r3.y), cw3, c3);
    }
    agg4[(size_t)n * 32 + hl] = make_float4(c0, c1, c2, c3);
    s0 += c0; s1 += c1; s2 += c2; s3 += c3;
    q0 += c0 * c0; q1 += c1 * c1; q2 += c2 * c2; q3 += c3 * c3;
  }
  s0 += __shfl_xor(s0, 32); s1 += __shfl_xor(s1, 32);
  s2 += __shfl_xor(s2, 32); s3 += __shfl_xor(s3, 32);
  q0 += __shfl_xor(q0, 32); q1 += __shfl_xor(q1, 32);
  q2 += __shfl_xor(q2, 32); q3 += __shfl_xor(q3, 32);
  __shared__ float red[4][128];
  int w = tid >> 6;
  if (half == 0) {
    red[w][4 * hl + 0] = s0; red[w][4 * hl + 1] = s1;
    red[w][4 * hl + 2] = s2; red[w][4 * hl + 3] = s3;
  }
  __syncthreads();
  if (w == 0) {
    float a = red[0][2 * lane] + red[1][2 * lane] + red[2][2 * lane] + red[3][2 * lane];
    float b = red[0][2 * lane + 1] + red[1][2 * lane + 1] + red[2][2 * lane + 1] + red[3][2 * lane + 1];
    atomicAdd(&stats[2 * lane], a);
    atomicAdd(&stats[2 * lane + 1], b);
  }
  __syncthreads();
  if (half == 0) {
    red[w][4 * hl + 0] = q0; red[w][4 * hl + 1] = q1;
    red[w][4 * hl + 2] = q2; red[w][4 * hl + 3] = q3;
  }
  __syncthreads();
  if (w == 0) {
    float a = red[0][2 * lane] + red[1][2 * lane] + red[2][2 * lane] + red[3][2 * lane];
    float b = red[0][2 * lane + 1] + red[1][2 * lane + 1] + red[2][2 * lane + 1] + red[3][2 * lane + 1];
    atomicAdd(&stats[128 + 2 * lane], a);
    atomicAdd(&stats[128 + 2 * lane + 1], b);
  }
}

// ---------------- BN(train) + ReLU + residual (bf16 x chain, in-place) ----------------
__global__ void bn_relu_res(const float4* __restrict__ agg4, const float* __restrict__ stats,
                            const float* __restrict__ gamma, const float* __restrict__ beta,
                            uint2* __restrict__ xb) {
  size_t idx = (size_t)blockIdx.x * 256 + threadIdx.x;  // float4 / uint2 index
  if (idx >= (size_t)N_NODES * 32) return;
  int c = ((int)(idx & 31)) * 4;
  const float n_inv = 1.f / (float)N_NODES;
  float sc[4], bc[4];
#pragma unroll
  for (int k = 0; k < 4; ++k) {
    float m = stats[c + k] * n_inv;
    float v = stats[128 + c + k] * n_inv - m * m;
    sc[k] = gamma[c + k] * rsqrtf(v + BN_EPS);
    bc[k] = beta[c + k] - m * sc[k];
  }
  float4 a = agg4[idx];
  uint2 xi = xb[idx];
  float r0 = fmaxf(fmaf(a.x, sc[0], bc[0]), 0.f) + blo(xi.x);
  float r1 = fmaxf(fmaf(a.y, sc[1], bc[1]), 0.f) + bhi(xi.x);
  float r2 = fmaxf(fmaf(a.z, sc[2], bc[2]), 0.f) + blo(xi.y);
  float r3 = fmaxf(fmaf(a.w, sc[3], bc[3]), 0.f) + bhi(xi.y);
  xb[idx] = make_uint2(pack2(r0, r1), pack2(r2, r3));
}

// ---------------- pooling (reads bf16 x) ----------------
__global__ void graph_starts(const int* __restrict__ batch, int* __restrict__ gstart) {
  int n = blockIdx.x * 256 + threadIdx.x;
  if (n >= N_NODES) return;
  int b = batch[n];
  int bp = (n == 0) ? -1 : batch[n - 1];
  for (int g = bp + 1; g <= b; ++g) gstart[g] = n;
  if (n == N_NODES - 1) {
    for (int g = b + 1; g <= BG; ++g) gstart[g] = N_NODES;
  }
}

__global__ __launch_bounds__(256) void pool_kernel(const uint32_t* __restrict__ xb,
                                                   const int* __restrict__ gstart,
                                                   float* __restrict__ pooled) {
  int g = blockIdx.x;
  int c = threadIdx.x & 127;
  int half = threadIdx.x >> 7;
  int s = gstart[g], e = gstart[g + 1];
  float acc = 0.f;
  for (int n = s + half; n < e; n += 2) {
    uint32_t u = xb[(size_t)n * 64 + (c >> 1)];
    acc += (c & 1) ? bhi(u) : blo(u);
  }
  __shared__ float red[256];
  red[threadIdx.x] = acc;
  __syncthreads();
  if (half == 0) {
    float v = red[c] + red[128 + c];
    int cnt = e - s;
    pooled[(size_t)g * 128 + c] = v / fmaxf((float)cnt, 1.f);
  }
}

// ---------------- f32 GEMM (MLP head only) ----------------
template <int RELU, int BIAS>
__global__ __launch_bounds__(256) void gemm_f32(const float* __restrict__ A,
                                                const float* __restrict__ W,
                                                const float* __restrict__ bias,
                                                float* __restrict__ Cmat,
                                                int M, int K, int N) {
  __shared__ float As[32][128];
  __shared__ float Bs[32][128];
  int tid = threadIdx.x;
  int row0 = blockIdx.x * 128, col0 = blockIdx.y * 128;
  int tx = tid & 15, ty = tid >> 4;
  float acc[8][8];
#pragma unroll
  for (int i = 0; i < 8; ++i)
#pragma unroll
    for (int j = 0; j < 8; ++j) acc[i][j] = 0.f;

  for (int k0 = 0; k0 < K; k0 += 32) {
    {
      int r = tid >> 1;
      int kseg = (tid & 1) * 16;
      bool valid = (row0 + r) < M;
      const float* ap = A + (size_t)(row0 + r) * K + k0 + kseg;
#pragma unroll
      for (int q = 0; q < 4; ++q) {
        float4 v;
        if (valid) v = *(const float4*)(ap + q * 4);
        else { v.x = v.y = v.z = v.w = 0.f; }
        As[kseg + q * 4 + 0][r] = v.x;
        As[kseg + q * 4 + 1][r] = v.y;
        As[kseg + q * 4 + 2][r] = v.z;
        As[kseg + q * 4 + 3][r] = v.w;
      }
    }
    {
      int kk = tid >> 3;
      int seg = (tid & 7) * 16;
      const float* wp = W + (size_t)(k0 + kk) * N + col0 + seg;
#pragma unroll
      for (int q = 0; q < 4; ++q)
        *(float4*)&Bs[kk][seg + q * 4] = *(const float4*)(wp + q * 4);
    }
    __syncthreads();
#pragma unroll
    for (int kk = 0; kk < 32; ++kk) {
      float4 a0 = *(const float4*)&As[kk][ty * 4];
      float4 a1 = *(const float4*)&As[kk][64 + ty * 4];
      float4 b0 = *(const float4*)&Bs[kk][tx * 4];
      float4 b1 = *(const float4*)&Bs[kk][64 + tx * 4];
      float av[8] = {a0.x, a0.y, a0.z, a0.w, a1.x, a1.y, a1.z, a1.w};
      float bv[8] = {b0.x, b0.y, b0.z, b0.w, b1.x, b1.y, b1.z, b1.w};
#pragma unroll
      for (int i = 0; i < 8; ++i)
#pragma unroll
        for (int j = 0; j < 8; ++j) acc[i][j] = fmaf(av[i], bv[j], acc[i][j]);
    }
    __syncthreads();
  }
#pragma unroll
  for (int i = 0; i < 8; ++i) {
    int r = row0 + ((i < 4) ? (ty * 4 + i) : (64 + ty * 4 + i - 4));
    if (r >= M) continue;
#pragma unroll
    for (int j = 0; j < 8; ++j) {
      int c = col0 + ((j < 4) ? (tx * 4 + j) : (64 + tx * 4 + j - 4));
      float v = acc[i][j];
      if (BIAS) v += bias[c];
      if (RELU) v = fmaxf(v, 0.f);
      Cmat[(size_t)r * N + c] = v;
    }
  }
}

// ---------------- host launch ----------------
extern "C" void kernel_launch(void* const* d_in, const int* in_sizes, int n_in,
                              void* d_out, int out_size, void* d_ws, size_t ws_size,
                              hipStream_t stream) {
  const float* x_in  = (const float*)d_in[0];
  const int*   eidx  = (const int*)d_in[1];
  const int*   batch = (const int*)d_in[2];
  const float* W1 = (const float*)d_in[3];
  const float* g1 = (const float*)d_in[5];
  const float* be1 = (const float*)d_in[6];
  const float* W2 = (const float*)d_in[7];
  const float* g2 = (const float*)d_in[9];
  const float* be2 = (const float*)d_in[10];
  const float* W3 = (const float*)d_in[11];
  const float* g3 = (const float*)d_in[13];
  const float* be3 = (const float*)d_in[14];
  const float* Wa = (const float*)d_in[15];
  const float* asrc = (const float*)d_in[16];
  const float* adst = (const float*)d_in[17];
  const float* ga = (const float*)d_in[19];
  const float* bea = (const float*)d_in[20];
  const float* Wh1 = (const float*)d_in[21];
  const float* bh1 = (const float*)d_in[22];
  const float* Wm0 = (const float*)d_in[23];
  const float* bm0 = (const float*)d_in[24];
  const float* Wm1 = (const float*)d_in[25];
  const float* bm1 = (const float*)d_in[26];
  const float* Wo = (const float*)d_in[27];
  const float* bo = (const float*)d_in[28];

  const int* src = eidx;
  const int* dst = eidx + N_EDGES;

  char* p = (char*)d_ws;
  auto alloc = [&](size_t bytes) {
    char* r = p;
    p += (bytes + 255) & ~(size_t)255;
    return r;
  };
  uint32_t* Hb     = (uint32_t*)alloc((size_t)N_NODES * 64 * 4);   // bf16-pair h
  uint32_t* xb     = (uint32_t*)alloc((size_t)N_NODES * 64 * 4);   // bf16-pair x
  float* agg       = (float*)alloc((size_t)N_NODES * CCH * 4);
  int2*  csr_sw    = (int2*)alloc((size_t)N_EDGES * 8);
  int*   rowstart  = (int*)alloc((size_t)(N_NODES + 1) * 4);
  int*   indeg     = (int*)alloc((size_t)2 * N_NODES * 4);
  int*   cursor    = indeg + N_NODES;
  float* dinv      = (float*)alloc((size_t)N_NODES * 4);
  float* es        = (float*)alloc((size_t)N_NODES * 4);
  float* ed        = (float*)alloc((size_t)N_NODES * 4);
  int*   chunksum  = (int*)alloc(128 * 4);
  float* stats     = (float*)alloc(4 * 256 * 4);
  int*   gstart    = (int*)alloc((BG + 1) * 4);
  float* pooled    = (float*)alloc((size_t)BG * CCH * 4);
  float* m1        = (float*)alloc((size_t)BG * NHID * 4);
  float* m2        = (float*)alloc((size_t)BG * NHID * 4);
  unsigned short* Wp1 = (unsigned short*)alloc(2048 * 8 * 2);
  unsigned short* Wp2 = (unsigned short*)alloc(2048 * 8 * 2);
  unsigned short* Wp3 = (unsigned short*)alloc(2048 * 8 * 2);
  unsigned short* Wp4 = (unsigned short*)alloc(2048 * 8 * 2);

  hipMemsetAsync(indeg, 0, (size_t)2 * N_NODES * 4, stream);
  hipMemsetAsync(stats, 0, 4 * 256 * 4, stream);

  // CSR build
  hist_kernel<<<(N_EDGES + 255) / 256, 256, 0, stream>>>(dst, indeg);
  scan_chunks<<<98, 256, 0, stream>>>(indeg, rowstart, chunksum);
  scan_sums<<<1, 128, 0, stream>>>(chunksum, 98);
  scan_add<<<(N_NODES + 256) / 256, 256, 0, stream>>>(rowstart, chunksum);
  compute_dinv<<<(N_NODES + 255) / 256, 256, 0, stream>>>(indeg, dinv);
  scatter_edges<<<(N_EDGES + 255) / 256, 256, 0, stream>>>(src, dst, rowstart, cursor, dinv, csr_sw);

  // bf16 prep
  const int el2_blocks = (N_NODES * 64 + 255) / 256;   // float2 granularity (cast)
  const int el4_blocks = (N_NODES * 32 + 255) / 256;   // float4 granularity (bn)
  cast_bf16_kernel<<<el2_blocks, 256, 0, stream>>>((const float2*)x_in, xb);
  pack_w_kernel<<<8, 256, 0, stream>>>(W1, Wp1);
  pack_w_kernel<<<8, 256, 0, stream>>>(W2, Wp2);
  pack_w_kernel<<<8, 256, 0, stream>>>(W3, Wp3);
  pack_w_kernel<<<8, 256, 0, stream>>>(Wa, Wp4);

  const int gemm_blocks_m = (N_NODES + 127) / 128;  // 782
  const int AGG_BLOCKS = 2048;                      // 8192 waves

  const unsigned short* Wps[3] = {Wp1, Wp2, Wp3};
  const float* gs[3] = {g1, g2, g3};
  const float* bes[3] = {be1, be2, be3};
  for (int l = 0; l < 3; ++l) {
    gemm_mfma<<<gemm_blocks_m, 256, 0, stream>>>(xb, Wps[l], Hb, N_NODES);
    gcn_agg<<<AGG_BLOCKS, 256, 0, stream>>>((const uint2*)Hb, rowstart, csr_sw, dinv,
                                            (float4*)agg, stats + l * 256);
    bn_relu_res<<<el4_blocks, 256, 0, stream>>>((const float4*)agg, stats + l * 256,
                                                gs[l], bes[l], (uint2*)xb);
  }

  // GAT layer
  gemm_mfma<<<gemm_blocks_m, 256, 0, stream>>>(xb, Wp4, Hb, N_NODES);
  compute_esed<<<(N_NODES + 3) / 4, 256, 0, stream>>>(Hb, asrc, adst, es, ed);
  gat_pack_kernel<<<(N_EDGES + 255) / 256, 256, 0, stream>>>(csr_sw, es);
  gat_agg<<<AGG_BLOCKS, 256, 0, stream>>>((const uint2*)Hb, rowstart, csr_sw, es, ed,
                                          (float4*)agg, stats + 3 * 256);
  bn_relu_res<<<el4_blocks, 256, 0, stream>>>((const float4*)agg, stats + 3 * 256,
                                              ga, bea, (uint2*)xb);

  // pooling
  graph_starts<<<(N_NODES + 255) / 256, 256, 0, stream>>>(batch, gstart);
  pool_kernel<<<BG, 256, 0, stream>>>(xb, gstart, pooled);

  // MLP head (f32)
  gemm_f32<1, 1><<<dim3(4, 4), 256, 0, stream>>>(pooled, Wh1, bh1, m1, BG, CCH, NHID);
  gemm_f32<1, 1><<<dim3(4, 4), 256, 0, stream>>>(m1, Wm0, bm0, m2, BG, NHID, NHID);
  gemm_f32<1, 1><<<dim3(4, 4), 256, 0, stream>>>(m2, Wm1, bm1, m1, BG, NHID, NHID);
  gemm_f32<0, 1><<<dim3(4, 2), 256, 0, stream>>>(m1, Wo, bo, (float*)d_out, BG, NHID, NOUT);
}